// Round 7
// baseline (1396.957 us; speedup 1.0000x reference)
//
#include <hip/hip_runtime.h>
#include <math.h>

#define NPTS  8192
#define NB    2
#define NTOT  (NPTS*NB)
#define GD    60
#define NCELL (GD*GD*GD)
#define TOTC  (NB*NCELL)
#define HCELL 0.2f
#define INVH  5.0f
#define ORGN  (-6.0f)
#define NN    8192
#define SCAN_CHUNK 1024
#define NBLK_SCAN  ((TOTC + SCAN_CHUNK - 1) / SCAN_CHUNK)
#define NTILE (NTOT / 64)   // 256 query tiles, one wave each

// ---------------- workspace layout (bytes) ----------------
#define OFF_CNT     ((size_t)0)
#define OFF_OFFS    (OFF_CNT    + (size_t)TOTC*4)
#define OFF_CELLID  (OFF_OFFS   + (size_t)TOTC*4)
#define OFF_RANK    (OFF_CELLID + (size_t)NTOT*4)
#define OFF_SPOS    (OFF_RANK   + (size_t)NTOT*4)          // float4 * NTOT (w = origidx bits)
#define OFF_KNN     (OFF_SPOS   + (size_t)NTOT*16)         // int * NTOT*16
#define OFF_SPATIAL (OFF_KNN    + (size_t)NTOT*16*4)       // [B,4,N]
#define OFF_XT      (OFF_SPATIAL+ (size_t)NB*4*NPTS*4)     // [B,N,128]
#define OFF_MD      (OFF_XT     + (size_t)NB*128*NPTS*4)   // [B,128,N]
#define OFF_S1      (OFF_MD     + (size_t)NB*128*NPTS*4)   // [B,32,N]
#define OFF_SF      (OFF_S1     + (size_t)NB*32*NPTS*4)    // [B,64,N]
#define OFF_Y1      (OFF_SF     + (size_t)NB*64*NPTS*4)    // [B,128,N]
#define OFF_Y2      (OFF_Y1     + (size_t)NB*128*NPTS*4)   // [B,128,N]
#define OFF_A1      (OFF_Y2     + (size_t)NB*128*NPTS*4)   // [B,64,N]
#define OFF_SC      (OFF_A1     + (size_t)NB*64*NPTS*4)    // 1088 floats
#define OFF_BSUM    (OFF_SC     + (size_t)1088*4)          // NBLK_SCAN ints
#define OFF_BPRE    (OFF_BSUM   + (size_t)NBLK_SCAN*4)     // NBLK_SCAN ints
#define OFF_RNG     (((OFF_BPRE + (size_t)NBLK_SCAN*4) + 15) & ~(size_t)15)  // int2 * TOTC

// Replicate reference arithmetic exactly (no fma contraction).
static __device__ __forceinline__ float sumsq3(float x, float y, float z) {
    return __fadd_rn(__fadd_rn(__fmul_rn(x, x), __fmul_rn(y, y)), __fmul_rn(z, z));
}
// monotone unsigned key for float (handles tiny negative self-distance)
static __device__ __forceinline__ unsigned fkey(float f) {
    unsigned b = __float_as_uint(f);
    return b ^ ((unsigned)(((int)b) >> 31) | 0x80000000u);
}
static __device__ __forceinline__ float wred_max(float v) {
    #pragma unroll
    for (int o = 32; o > 0; o >>= 1) v = fmaxf(v, __shfl_xor(v, o, 64));
    return v;
}
static __device__ __forceinline__ float wred_min(float v) {
    #pragma unroll
    for (int o = 32; o > 0; o >>= 1) v = fminf(v, __shfl_xor(v, o, 64));
    return v;
}

// ---------------- grid build ----------------
__global__ void cell_build(const float* __restrict__ xyz, int* __restrict__ cnt,
                           int* __restrict__ cellid, int* __restrict__ rank) {
    int t = blockIdx.x * 256 + threadIdx.x;
    if (t >= NTOT) return;
    const float* p = xyz + (size_t)t * 3;
    float x = p[0], y = p[1], z = p[2];
    int cx = min(GD - 1, max(0, (int)floorf((x - ORGN) * INVH)));
    int cy = min(GD - 1, max(0, (int)floorf((y - ORGN) * INVH)));
    int cz = min(GD - 1, max(0, (int)floorf((z - ORGN) * INVH)));
    int gcell = (t >> 13) * NCELL + (cz * GD + cy) * GD + cx;
    rank[t] = atomicAdd(&cnt[gcell], 1);
    cellid[t] = gcell;
}

// -------- hierarchical exclusive scan of cnt[TOTC] -> offs[TOTC] (+rng int2) --------
__global__ __launch_bounds__(256) void scan_sums(const int* __restrict__ cnt, int* __restrict__ bsum) {
    __shared__ int red[256];
    int blk = blockIdx.x, t = threadIdx.x;
    int i0 = blk * SCAN_CHUNK + t * 4;
    int s = 0;
    if (i0 + 3 < TOTC) {
        int4 v = *(const int4*)(cnt + i0);
        s = v.x + v.y + v.z + v.w;
    } else {
        for (int j = 0; j < 4; ++j) if (i0 + j < TOTC) s += cnt[i0 + j];
    }
    red[t] = s;
    __syncthreads();
    for (int d = 128; d > 0; d >>= 1) {
        if (t < d) red[t] += red[t + d];
        __syncthreads();
    }
    if (t == 0) bsum[blk] = red[0];
}

__global__ __launch_bounds__(512) void scan_top(const int* __restrict__ bsum, int* __restrict__ bpre) {
    __shared__ int ps[512];
    int t = threadIdx.x;
    int v = (t < NBLK_SCAN) ? bsum[t] : 0;
    ps[t] = v;
    __syncthreads();
    for (int d = 1; d < 512; d <<= 1) {
        int u = 0;
        if (t >= d) u = ps[t - d];
        __syncthreads();
        ps[t] += u;
        __syncthreads();
    }
    if (t < NBLK_SCAN) bpre[t] = ps[t] - v;   // exclusive
}

__global__ __launch_bounds__(256) void scan_write(const int* __restrict__ cnt, const int* __restrict__ bpre,
                                                  int* __restrict__ offs, int2* __restrict__ rng) {
    __shared__ int ps[256];
    int blk = blockIdx.x, t = threadIdx.x;
    int i0 = blk * SCAN_CHUNK + t * 4;
    int a = 0, b = 0, c = 0, d = 0;
    if (i0 + 3 < TOTC) {
        int4 v = *(const int4*)(cnt + i0);
        a = v.x; b = v.y; c = v.z; d = v.w;
    } else {
        if (i0 + 0 < TOTC) a = cnt[i0 + 0];
        if (i0 + 1 < TOTC) b = cnt[i0 + 1];
        if (i0 + 2 < TOTC) c = cnt[i0 + 2];
        if (i0 + 3 < TOTC) d = cnt[i0 + 3];
    }
    int s = a + b + c + d;
    ps[t] = s;
    __syncthreads();
    for (int dd = 1; dd < 256; dd <<= 1) {
        int u = 0;
        if (t >= dd) u = ps[t - dd];
        __syncthreads();
        ps[t] += u;
        __syncthreads();
    }
    int base = bpre[blk] + ps[t] - s;
    if (i0 + 3 < TOTC) {
        offs[i0 + 0] = base;
        offs[i0 + 1] = base + a;
        offs[i0 + 2] = base + a + b;
        offs[i0 + 3] = base + a + b + c;
        *(int4*)(rng + i0)     = make_int4(base, base + a, base + a, base + a + b);
        *(int4*)(rng + i0 + 2) = make_int4(base + a + b, base + a + b + c,
                                           base + a + b + c, base + s);
    } else {
        if (i0 + 0 < TOTC) { offs[i0 + 0] = base;             rng[i0 + 0] = make_int2(base, base + a); }
        if (i0 + 1 < TOTC) { offs[i0 + 1] = base + a;         rng[i0 + 1] = make_int2(base + a, base + a + b); }
        if (i0 + 2 < TOTC) { offs[i0 + 2] = base + a + b;     rng[i0 + 2] = make_int2(base + a + b, base + a + b + c); }
        if (i0 + 3 < TOTC) { offs[i0 + 3] = base + a + b + c; rng[i0 + 3] = make_int2(base + a + b + c, base + s); }
    }
}

__global__ void scatter_k(const float* __restrict__ xyz, const int* __restrict__ cellid,
                          const int* __restrict__ rank, const int* __restrict__ offs,
                          float4* __restrict__ spos) {
    int t = blockIdx.x * 256 + threadIdx.x;
    if (t >= NTOT) return;
    const float* p = xyz + (size_t)t * 3;
    float x = p[0], y = p[1], z = p[2];
    int pos = offs[cellid[t]] + rank[t];
    spos[pos] = make_float4(x, y, z, __int_as_float(t & (NPTS - 1)));
}

// ---------------- exact KNN: one wave = 64 queries (one per LANE) ----------------
// R13 redesign. 256 waves total (1/CU) — the ~4-blocks/CU residency cap that
// limited R9-R12 no longer binds; duration = slowest tile. Wave streams ONE
// shared candidate stream (coalesced global -> LDS -> broadcast reads); each
// lane keeps its own query's top-16 in 16 u64 REGISTERS (drop-max). No
// per-candidate shuffles/ballots/prefix-scans at all.
// Exactness (standard kNN expansion):
//  - buffer invariant: regs hold the 16 smallest keys of the stream seen.
//  - z-slabs visited outward (two pointers); a slab is skipped only when its
//    min-dz^2 (with slack) > wave-max(curmax_d); curmax only decreases, so any
//    skipped point is strictly farther than every lane's final 16th.
//  - each visited slab streamed over y-rows [min qy - w, max qy + w], with
//    w = sqrt(wave-max curmax_d) + cushion at VISIT time >= final radius ->
//    same monotonicity argument covers y-pruned points.
//  - own slab: warm window first (heuristic), then revisited once as
//    window-minus-warm (range split -> no duplicates).
//  - unfilled lanes keep curmax = 1e30 -> windows stay full, never stops early.
//  - keys = (fkey(d)<<27)|(oi<<14)|slot: same exact arithmetic (pdist4 form,
//    pxx precomputed with identical _rn ops) and tie-break as R5-proven code.
//  - early-reject dy^2+dz^2 > curmax_d + 1e-3: slack >> fp error (~1e-4), and
//    strictly-greater rejection cannot touch ties.
// Top-16 is consumed downstream as a SET (max over K / means) -> no sort.
__global__ __launch_bounds__(64) void knn_kernel(const float4* __restrict__ spos,
                                                 const int2* __restrict__ rng,
                                                 int* __restrict__ knn,
                                                 float* __restrict__ spatial) {
    __shared__ float4 bufA[64];      // (px,py,pz,pxx)
    __shared__ unsigned bufB[64];    // (oi<<14)|slot
    int lane = threadIdx.x;
    int tl = blockIdx.x;
    int tile = (tl & 7) * (NTILE / 8) + (tl >> 3);   // XCD-chunked (256%8==0, bijective)
    int s = tile * 64 + lane;
    float4 q = spos[s];
    float qx = q.x, qy = q.y, qz = q.z;
    float qxx = sumsq3(qx, qy, qz);
    int b  = s >> 13;
    int nq = __float_as_int(q.w);
    int cy = min(GD - 1, max(0, (int)floorf((qy - ORGN) * INVH)));
    int cz = min(GD - 1, max(0, (int)floorf((qz - ORGN) * INVH)));
    const int2* rg = rng + b * NCELL;

    unsigned long long kb[16];
    #pragma unroll
    for (int i = 0; i < 16; ++i) kb[i] = ~0ULL;
    unsigned long long kmax = ~0ULL;
    float cmax_d = 1e30f;

    // stream a contiguous slot range; all lanes process every candidate
    auto stream_range = [&](int r0, int r1) {
        if (r0 >= r1) return;
        int base = r0;
        float4 pc = make_float4(0.f, 0.f, 0.f, 0.f);
        unsigned lc = 0;
        if (lane < r1 - base) {
            float4 p = spos[base + lane];
            lc = ((unsigned)__float_as_int(p.w) << 14) | ((unsigned)(base + lane) & 0x3FFFu);
            p.w = sumsq3(p.x, p.y, p.z);
            pc = p;
        }
        while (base < r1) {
            int nb = base + 64;
            float4 pn = make_float4(0.f, 0.f, 0.f, 0.f);
            unsigned ln = 0;
            if (nb < r1 && lane < r1 - nb) {        // prefetch next chunk (in flight)
                float4 p = spos[nb + lane];
                ln = ((unsigned)__float_as_int(p.w) << 14) | ((unsigned)(nb + lane) & 0x3FFFu);
                p.w = sumsq3(p.x, p.y, p.z);
                pn = p;
            }
            int n = min(64, r1 - base);
            bufA[lane] = pc;
            bufB[lane] = lc;
            asm volatile("s_waitcnt lgkmcnt(0)" ::: "memory");
            __builtin_amdgcn_sched_barrier(0);
            #pragma unroll 4
            for (int j = 0; j < n; ++j) {
                float4 c = bufA[j];                 // broadcast read
                unsigned lo = bufB[j];
                float dy = c.y - qy, dz = c.z - qz;
                float s2 = dy * dy + dz * dz;
                if (s2 <= cmax_d + 1e-3f) {
                    float dot = __fadd_rn(__fadd_rn(__fmul_rn(qx, c.x), __fmul_rn(qy, c.y)),
                                          __fmul_rn(qz, c.z));
                    float d = __fsub_rn(__fadd_rn(qxx, c.w), __fadd_rn(dot, dot));
                    unsigned long long key = ((unsigned long long)fkey(d) << 27) | lo;
                    if (key < kmax) {
                        bool rep = false;
                        #pragma unroll
                        for (int i = 0; i < 16; ++i) {
                            bool hit = (!rep) && (kb[i] == kmax);
                            kb[i] = hit ? key : kb[i];
                            rep = rep || hit;
                        }
                        unsigned long long m = kb[0];
                        #pragma unroll
                        for (int i = 1; i < 16; ++i) m = (kb[i] > m) ? kb[i] : m;
                        kmax = m;
                        if (m == ~0ULL) {
                            cmax_d = 1e30f;
                        } else {
                            unsigned u = (unsigned)(m >> 27);
                            cmax_d = __uint_as_float((u & 0x80000000u) ? (u & 0x7FFFFFFFu) : ~u);
                        }
                    }
                }
            }
            asm volatile("s_waitcnt lgkmcnt(0)" ::: "memory");
            __builtin_amdgcn_sched_barrier(0);
            pc = pn; lc = ln; base = nb;
        }
    };

    // wave query extents
    float qymin = wred_min(qy), qymax = wred_max(qy);
    float qzmin = wred_min(qz), qzmax = wred_max(qz);
    int ymin_c = min(GD - 1, max(0, (int)floorf((qymin - ORGN) * INVH)));
    int ymax_c = min(GD - 1, max(0, (int)floorf((qymax - ORGN) * INVH)));
    int zmed = __shfl(cz, 32, 64);
    (void)cy;

    // warm start: own slab, tile rows +-2
    int wy0 = max(0, ymin_c - 2), wy1 = min(GD - 1, ymax_c + 2);
    {
        int r0 = rg[(zmed * GD + wy0) * GD].x;
        int r1 = rg[(zmed * GD + wy1) * GD + (GD - 1)].y;
        stream_range(r0, r1);
    }

    // outward slab expansion with monotone y-windows
    int up = zmed + 1, dn = zmed - 1;
    bool ownPend = true;
    while (true) {
        float rmax_d = wred_max(cmax_d);
        float w = sqrtf(fminf(fmaxf(rmax_d, 0.f), 1e28f)) + 1e-3f;
        int y0 = (int)fmaxf(fminf(floorf((qymin - w - ORGN) * INVH), (float)(GD - 1)), 0.f);
        int y1 = (int)fmaxf(fminf(floorf((qymax + w - ORGN) * INVH), (float)(GD - 1)), 0.f);
        if (ownPend) {
            ownPend = false;
            if (y0 < wy0) {
                int r0 = rg[(zmed * GD + y0) * GD].x;
                int r1 = rg[(zmed * GD + (wy0 - 1)) * GD + (GD - 1)].y;
                stream_range(r0, r1);
            }
            if (y1 > wy1) {
                int r0 = rg[(zmed * GD + (wy1 + 1)) * GD].x;
                int r1 = rg[(zmed * GD + y1) * GD + (GD - 1)].y;
                stream_range(r0, r1);
            }
            continue;   // recompute rmax/window before first expansion slab
        }
        float dzu = (up < GD) ? fmaxf((ORGN + (float)up * HCELL) - qzmax, 0.f) : 1e30f;
        float dzd = (dn >= 0) ? fmaxf(qzmin - (ORGN + (float)(dn + 1) * HCELL), 0.f) : 1e30f;
        bool upok = (up < GD) && (dzu * dzu - 2e-3f <= rmax_d);
        bool dnok = (dn >= 0) && (dzd * dzd - 2e-3f <= rmax_d);
        if (!upok && !dnok) break;
        int zc;
        if (upok && (!dnok || dzu <= dzd)) { zc = up; ++up; }
        else                               { zc = dn; --dn; }
        int r0 = rg[(zc * GD + y0) * GD].x;
        int r1 = rg[(zc * GD + y1) * GD + (GD - 1)].y;
        stream_range(r0, r1);
    }

    // epilogue: per-lane outputs (set semantics; rank order irrelevant downstream)
    float rxs = 0.f, rys = 0.f, rzs = 0.f, rds = 0.f;
    size_t outb = (((size_t)b << 13) + nq) * 16;
    #pragma unroll
    for (int i = 0; i < 16; ++i) {
        int slot = (int)(kb[i] & 0x3FFFu);
        int oi   = (int)((kb[i] >> 14) & 0x1FFFu);
        float4 p = spos[slot];
        float rx = p.x - qx, ry = p.y - qy, rz = p.z - qz;
        float dl = sqrtf(__fadd_rn(__fadd_rn(__fmul_rn(rx, rx), __fmul_rn(ry, ry)), __fmul_rn(rz, rz)));
        knn[outb + i] = oi;
        rxs += rx; rys += ry; rzs += rz; rds += dl;
    }
    const float inv16 = 0.0625f;
    spatial[((size_t)b * 4 + 0) * NPTS + nq] = rxs * inv16;
    spatial[((size_t)b * 4 + 1) * NPTS + nq] = rys * inv16;
    spatial[((size_t)b * 4 + 2) * NPTS + nq] = rzs * inv16;
    spatial[((size_t)b * 4 + 3) * NPTS + nq] = rds * inv16;
}

// ---------------- x[B,C,N] -> xT[B,N,C] ----------------
__global__ void transpose_k(const float* __restrict__ x, float* __restrict__ xT) {
    __shared__ float tl[32][33];
    int b = blockIdx.z;
    int n0 = blockIdx.x * 32, c0 = blockIdx.y * 32;
    int tx = threadIdx.x, ty = threadIdx.y;
    const float* xb = x + (size_t)b * 128 * NN;
    float* xtb = xT + (size_t)b * NN * 128;
    for (int i = 0; i < 32; i += 8) tl[ty + i][tx] = xb[(size_t)(c0 + ty + i) * NN + n0 + tx];
    __syncthreads();
    for (int i = 0; i < 32; i += 8) xtb[(size_t)(n0 + ty + i) * 128 + c0 + tx] = tl[tx][ty + i];
}

// ---------------- max_k(x[:,idx_k]) - x  -> md[B,128,N] ----------------
__global__ __launch_bounds__(256) void md_k(const float* __restrict__ xT,
                                            const int* __restrict__ knn,
                                            float* __restrict__ md) {
    __shared__ int ki[8][16];
    __shared__ float smd[8][132];
    int b = blockIdx.y;
    int n0 = blockIdx.x * 8;
    int tid = threadIdx.x;
    if (tid < 128) ki[tid >> 4][tid & 15] = knn[(((size_t)b << 13) + n0 + (tid >> 4)) * 16 + (tid & 15)];
    __syncthreads();
    int nl = tid >> 5;
    int c4 = (tid & 31) * 4;
    const float* xb = xT + (size_t)b * NPTS * 128;
    float4 m = make_float4(-3.0e38f, -3.0e38f, -3.0e38f, -3.0e38f);
    #pragma unroll
    for (int k = 0; k < 16; ++k) {
        const float4 g = *(const float4*)(xb + (size_t)ki[nl][k] * 128 + c4);
        m.x = fmaxf(m.x, g.x); m.y = fmaxf(m.y, g.y); m.z = fmaxf(m.z, g.z); m.w = fmaxf(m.w, g.w);
    }
    const float4 own = *(const float4*)(xb + (size_t)(n0 + nl) * 128 + c4);
    m.x -= own.x; m.y -= own.y; m.z -= own.z; m.w -= own.w;
    *(float4*)(&smd[nl][c4]) = m;
    __syncthreads();
    for (int r = 0; r < 4; ++r) {
        int c = (tid >> 3) + 32 * r;
        int n2 = tid & 7;
        md[((size_t)b * 128 + c) * NN + n0 + n2] = smd[n2][c];
    }
}

// ---------------- fold conv-bias + BN into per-channel scale/shift ----------------
__global__ void prep_k(const float* bb1, const float* g1, const float* be1, const float* m1, const float* v1,
                       const float* bb2, const float* g2, const float* be2, const float* m2, const float* v2,
                       const float* sb1, const float* gs,  const float* bes, const float* ms, const float* vs,
                       const float* sb2,
                       const float* ab1, const float* ga,  const float* bea, const float* ma, const float* va,
                       const float* ab2, float* sc) {
    int t = threadIdx.x;
    if (t < 128) {
        float i1 = g1[t] / sqrtf(v1[t] + 1e-5f);
        sc[t] = i1;        sc[128 + t] = bb1[t] * i1 + be1[t] - m1[t] * i1;
        float i2 = g2[t] / sqrtf(v2[t] + 1e-5f);
        sc[256 + t] = i2;  sc[384 + t] = bb2[t] * i2 + be2[t] - m2[t] * i2;
        sc[832 + t] = 1.0f; sc[960 + t] = ab2[t];
    }
    if (t < 32) {
        float is = gs[t] / sqrtf(vs[t] + 1e-5f);
        sc[512 + t] = is;  sc[544 + t] = sb1[t] * is + bes[t] - ms[t] * is;
    }
    if (t < 64) {
        sc[576 + t] = 1.0f; sc[640 + t] = sb2[t];
        float ia = ga[t] / sqrtf(va[t] + 1e-5f);
        sc[704 + t] = ia;  sc[768 + t] = ab1[t] * ia + bea[t] - ma[t] * ia;
    }
}

// ---------------- generic 1x1-conv (+folded BN, activation) ----------------
// ACT: 0=none, 1=relu, 2=sigmoid + fused "dout = x + y2*attn"
template <int O, int K, int TILE_N, int SPLIT, int ACT>
__global__ __launch_bounds__(256) void conv_bn(const float* __restrict__ srcA,
                                               const float* __restrict__ srcB,
                                               const float* __restrict__ W,
                                               const float* __restrict__ scale,
                                               const float* __restrict__ shift,
                                               float* __restrict__ out,
                                               const float* __restrict__ resx,
                                               const float* __restrict__ y2,
                                               float* __restrict__ dout) {
    constexpr int KC  = (K < 64) ? K : 64;
    constexpr int NT4 = TILE_N / 4;
    constexpr int O4  = O / 4;
    static_assert(NT4 * O4 == 256, "thread mapping");
    __shared__ float wT[KC][O + 4];
    __shared__ float inT[KC][TILE_N];
    int tid = threadIdx.x;
    int b = blockIdx.z;
    int n0 = blockIdx.x * TILE_N;
    int n_thr = tid % NT4;          // n fastest -> coalesced stores
    int o_thr = tid / NT4;
    float acc[4][4] = {{0.f, 0.f, 0.f, 0.f}, {0.f, 0.f, 0.f, 0.f}, {0.f, 0.f, 0.f, 0.f}, {0.f, 0.f, 0.f, 0.f}};

    for (int k0 = 0; k0 < K; k0 += KC) {
        for (int idx = tid; idx < KC * O; idx += 256) {
            int cc = idx % KC;
            int o  = idx / KC;
            wT[cc][o] = W[(size_t)o * K + k0 + cc];
        }
        for (int idx = tid; idx < KC * NT4; idx += 256) {
            int cc = idx / NT4;
            int nf = idx % NT4;
            int cg = k0 + cc;
            const float* src = (cg < SPLIT)
                ? (srcA + ((size_t)b * SPLIT + cg) * NN)
                : (srcB + ((size_t)b * (K - SPLIT) + (cg - SPLIT)) * NN);
            *(float4*)(&inT[cc][nf * 4]) = *(const float4*)(src + n0 + nf * 4);
        }
        __syncthreads();
        #pragma unroll 8
        for (int c = 0; c < KC; ++c) {
            float4 wv = *(const float4*)(&wT[c][o_thr * 4]);
            float4 iv = *(const float4*)(&inT[c][n_thr * 4]);
            acc[0][0] = fmaf(wv.x, iv.x, acc[0][0]); acc[0][1] = fmaf(wv.x, iv.y, acc[0][1]);
            acc[0][2] = fmaf(wv.x, iv.z, acc[0][2]); acc[0][3] = fmaf(wv.x, iv.w, acc[0][3]);
            acc[1][0] = fmaf(wv.y, iv.x, acc[1][0]); acc[1][1] = fmaf(wv.y, iv.y, acc[1][1]);
            acc[1][2] = fmaf(wv.y, iv.z, acc[1][2]); acc[1][3] = fmaf(wv.y, iv.w, acc[1][3]);
            acc[2][0] = fmaf(wv.z, iv.x, acc[2][0]); acc[2][1] = fmaf(wv.z, iv.y, acc[2][1]);
            acc[2][2] = fmaf(wv.z, iv.z, acc[2][2]); acc[2][3] = fmaf(wv.z, iv.w, acc[2][3]);
            acc[3][0] = fmaf(wv.w, iv.x, acc[3][0]); acc[3][1] = fmaf(wv.w, iv.y, acc[3][1]);
            acc[3][2] = fmaf(wv.w, iv.z, acc[3][2]); acc[3][3] = fmaf(wv.w, iv.w, acc[3][3]);
        }
        __syncthreads();
    }
    #pragma unroll
    for (int j = 0; j < 4; ++j) {
        int o = o_thr * 4 + j;
        float scv = scale[o], shv = shift[o];
        float4 v;
        v.x = fmaf(acc[j][0], scv, shv);
        v.y = fmaf(acc[j][1], scv, shv);
        v.z = fmaf(acc[j][2], scv, shv);
        v.w = fmaf(acc[j][3], scv, shv);
        size_t obase = ((size_t)b * O + o) * NN + n0 + n_thr * 4;
        if (ACT == 1) {
            v.x = fmaxf(v.x, 0.f); v.y = fmaxf(v.y, 0.f); v.z = fmaxf(v.z, 0.f); v.w = fmaxf(v.w, 0.f);
            *(float4*)(out + obase) = v;
        } else if (ACT == 2) {
            float4 xr = *(const float4*)(resx + obase);
            float4 yr = *(const float4*)(y2 + obase);
            v.x = xr.x + yr.x / (1.f + __expf(-v.x));
            v.y = xr.y + yr.y / (1.f + __expf(-v.y));
            v.z = xr.z + yr.z / (1.f + __expf(-v.z));
            v.w = xr.w + yr.w / (1.f + __expf(-v.w));
            *(float4*)(dout + obase) = v;
        } else {
            *(float4*)(out + obase) = v;
        }
    }
}

extern "C" void kernel_launch(void* const* d_in, const int* in_sizes, int n_in,
                              void* d_out, int out_size, void* d_ws, size_t ws_size,
                              hipStream_t stream) {
    (void)in_sizes; (void)n_in; (void)out_size; (void)ws_size;
    const float* x    = (const float*)d_in[0];
    const float* xyz  = (const float*)d_in[1];
    const float* bw1  = (const float*)d_in[2];
    const float* bb1  = (const float*)d_in[3];
    const float* bn1g = (const float*)d_in[4];
    const float* bn1b = (const float*)d_in[5];
    const float* bn1m = (const float*)d_in[6];
    const float* bn1v = (const float*)d_in[7];
    const float* bw2  = (const float*)d_in[8];
    const float* bb2  = (const float*)d_in[9];
    const float* bn2g = (const float*)d_in[10];
    const float* bn2b = (const float*)d_in[11];
    const float* bn2m = (const float*)d_in[12];
    const float* bn2v = (const float*)d_in[13];
    const float* sw1  = (const float*)d_in[14];
    const float* sb1  = (const float*)d_in[15];
    const float* sbng = (const float*)d_in[16];
    const float* sbnb = (const float*)d_in[17];
    const float* sbnm = (const float*)d_in[18];
    const float* sbnv = (const float*)d_in[19];
    const float* sw2  = (const float*)d_in[20];
    const float* sb2  = (const float*)d_in[21];
    const float* aw1  = (const float*)d_in[22];
    const float* ab1  = (const float*)d_in[23];
    const float* abng = (const float*)d_in[24];
    const float* abnb = (const float*)d_in[25];
    const float* abnm = (const float*)d_in[26];
    const float* abnv = (const float*)d_in[27];
    const float* aw2  = (const float*)d_in[28];
    const float* ab2  = (const float*)d_in[29];

    char* ws = (char*)d_ws;
    int*    cnt    = (int*)(ws + OFF_CNT);
    int*    offs   = (int*)(ws + OFF_OFFS);
    int*    cellid = (int*)(ws + OFF_CELLID);
    int*    rank   = (int*)(ws + OFF_RANK);
    float4* spos   = (float4*)(ws + OFF_SPOS);
    int*    knn    = (int*)(ws + OFF_KNN);
    float*  spat   = (float*)(ws + OFF_SPATIAL);
    float*  xT     = (float*)(ws + OFF_XT);
    float*  md     = (float*)(ws + OFF_MD);
    float*  s1b    = (float*)(ws + OFF_S1);
    float*  sfb    = (float*)(ws + OFF_SF);
    float*  y1b    = (float*)(ws + OFF_Y1);
    float*  y2b    = (float*)(ws + OFF_Y2);
    float*  a1b    = (float*)(ws + OFF_A1);
    float*  sc     = (float*)(ws + OFF_SC);
    int*    bsum   = (int*)(ws + OFF_BSUM);
    int*    bpre   = (int*)(ws + OFF_BPRE);
    int2*   rng    = (int2*)(ws + OFF_RNG);
    float*  dout   = (float*)d_out;

    hipMemsetAsync(cnt, 0, (size_t)TOTC * 4, stream);
    cell_build<<<dim3((NTOT + 255) / 256), 256, 0, stream>>>(xyz, cnt, cellid, rank);
    scan_sums<<<dim3(NBLK_SCAN), 256, 0, stream>>>(cnt, bsum);
    scan_top<<<dim3(1), 512, 0, stream>>>(bsum, bpre);
    scan_write<<<dim3(NBLK_SCAN), 256, 0, stream>>>(cnt, bpre, offs, rng);
    scatter_k<<<dim3((NTOT + 255) / 256), 256, 0, stream>>>(xyz, cellid, rank, offs, spos);
    knn_kernel<<<dim3(NTILE), 64, 0, stream>>>(spos, rng, knn, spat);
    transpose_k<<<dim3(NPTS / 32, 128 / 32, NB), dim3(32, 8), 0, stream>>>(x, xT);
    md_k<<<dim3(NPTS / 8, NB), 256, 0, stream>>>(xT, knn, md);
    prep_k<<<1, 128, 0, stream>>>(bb1, bn1g, bn1b, bn1m, bn1v,
                                  bb2, bn2g, bn2b, bn2m, bn2v,
                                  sb1, sbng, sbnb, sbnm, sbnv,
                                  sb2,
                                  ab1, abng, abnb, abnm, abnv,
                                  ab2, sc);
    // spatial MLP: 4->32 (bn,relu), 32->64
    conv_bn<32, 4, 128, 4, 1><<<dim3(NPTS / 128, 1, NB), 256, 0, stream>>>(
        spat, spat, sw1, sc + 512, sc + 544, s1b, nullptr, nullptr, nullptr);
    conv_bn<64, 32, 64, 32, 0><<<dim3(NPTS / 64, 1, NB), 256, 0, stream>>>(
        s1b, s1b, sw2, sc + 576, sc + 640, sfb, nullptr, nullptr, nullptr);
    // boundary net: [x;md] 256->128 (bn,relu), 128->128 (bn,relu)
    conv_bn<128, 256, 32, 128, 1><<<dim3(NPTS / 32, 1, NB), 256, 0, stream>>>(
        x, md, bw1, sc + 0, sc + 128, y1b, nullptr, nullptr, nullptr);
    conv_bn<128, 128, 32, 128, 1><<<dim3(NPTS / 32, 1, NB), 256, 0, stream>>>(
        y1b, y1b, bw2, sc + 256, sc + 384, y2b, nullptr, nullptr, nullptr);
    // attention: [x;sfeat] 192->64 (bn,relu), 64->128 sigmoid + final fuse
    conv_bn<64, 192, 64, 128, 1><<<dim3(NPTS / 64, 1, NB), 256, 0, stream>>>(
        x, sfb, aw1, sc + 704, sc + 768, a1b, nullptr, nullptr, nullptr);
    conv_bn<128, 64, 32, 64, 2><<<dim3(NPTS / 32, 1, NB), 256, 0, stream>>>(
        a1b, a1b, aw2, sc + 832, sc + 960, dout, x, y2b, dout);
}

// Round 8
// 329.688 us; speedup vs baseline: 4.2372x; 4.2372x over previous
//
#include <hip/hip_runtime.h>
#include <math.h>

#define NPTS  8192
#define NB    2
#define NTOT  (NPTS*NB)
#define GD    60
#define NCELL (GD*GD*GD)
#define TOTC  (NB*NCELL)
#define HCELL 0.2f
#define INVH  5.0f
#define ORGN  (-6.0f)
#define NN    8192
#define SCAN_CHUNK 1024
#define NBLK_SCAN  ((TOTC + SCAN_CHUNK - 1) / SCAN_CHUNK)
#define RSTART    2    // phase-B ball radius = margin(RSTART)
#define RESC      4    // escalation ball radius = margin(RESC)
#define SEL_CAP  1024  // appended-key list (u64, 8KB)

// ---------------- workspace layout (bytes) ----------------
#define OFF_CNT     ((size_t)0)
#define OFF_OFFS    (OFF_CNT    + (size_t)TOTC*4)
#define OFF_CELLID  (OFF_OFFS   + (size_t)TOTC*4)
#define OFF_RANK    (OFF_CELLID + (size_t)NTOT*4)
#define OFF_SPOS    (OFF_RANK   + (size_t)NTOT*4)          // float4 * NTOT (w = origidx bits)
#define OFF_KNN     (OFF_SPOS   + (size_t)NTOT*16)         // int * NTOT*16
#define OFF_SPATIAL (OFF_KNN    + (size_t)NTOT*16*4)       // [B,4,N]
#define OFF_XT      (OFF_SPATIAL+ (size_t)NB*4*NPTS*4)     // [B,N,128]
#define OFF_MD      (OFF_XT     + (size_t)NB*128*NPTS*4)   // [B,128,N]
#define OFF_S1      (OFF_MD     + (size_t)NB*128*NPTS*4)   // [B,32,N]
#define OFF_SF      (OFF_S1     + (size_t)NB*32*NPTS*4)    // [B,64,N]
#define OFF_Y1      (OFF_SF     + (size_t)NB*64*NPTS*4)    // [B,128,N]
#define OFF_Y2      (OFF_Y1     + (size_t)NB*128*NPTS*4)   // [B,128,N]
#define OFF_A1      (OFF_Y2     + (size_t)NB*128*NPTS*4)   // [B,64,N]
#define OFF_SC      (OFF_A1     + (size_t)NB*64*NPTS*4)    // 1088 floats
#define OFF_BSUM    (OFF_SC     + (size_t)1088*4)          // NBLK_SCAN ints
#define OFF_BPRE    (OFF_BSUM   + (size_t)NBLK_SCAN*4)     // NBLK_SCAN ints
#define OFF_RNG     (((OFF_BPRE + (size_t)NBLK_SCAN*4) + 15) & ~(size_t)15)  // int2 * TOTC

// Replicate reference arithmetic exactly (no fma contraction).
static __device__ __forceinline__ float sumsq3(float x, float y, float z) {
    return __fadd_rn(__fadd_rn(__fmul_rn(x, x), __fmul_rn(y, y)), __fmul_rn(z, z));
}
static __device__ __forceinline__ float pdist4(float qx, float qy, float qz, float qxx,
                                               float px, float py, float pz) {
    float pxx = sumsq3(px, py, pz);
    float dot = __fadd_rn(__fadd_rn(__fmul_rn(qx, px), __fmul_rn(qy, py)), __fmul_rn(qz, pz));
    return __fsub_rn(__fadd_rn(qxx, pxx), __fadd_rn(dot, dot));
}
// monotone unsigned key for float (handles tiny negative self-distance)
static __device__ __forceinline__ unsigned fkey(float f) {
    unsigned b = __float_as_uint(f);
    return b ^ ((unsigned)(((int)b) >> 31) | 0x80000000u);
}
static __device__ __forceinline__ unsigned long long shflx64(unsigned long long v, int m) {
    unsigned lo = __shfl_xor((unsigned)v, m, 64);
    unsigned hi = __shfl_xor((unsigned)(v >> 32), m, 64);
    return ((unsigned long long)hi << 32) | lo;
}
// inclusive wave prefix-sum (all 64 lanes active)
static __device__ __forceinline__ int wave_scan_incl(int v, int lane) {
    #pragma unroll
    for (int d = 1; d < 64; d <<= 1) {
        int u = __shfl_up(v, d, 64);
        v += (lane >= d) ? u : 0;
    }
    return v;
}
// key threshold from margin m (>0): all keys strictly below are certified-complete
static __device__ __forceinline__ unsigned long long tkmake(float m) {
    return ((unsigned long long)(fkey(__fsub_rn(__fmul_rn(m, m), 1e-4f)) + 1u)) << 27;
}

// ---------------- grid build ----------------
__global__ void cell_build(const float* __restrict__ xyz, int* __restrict__ cnt,
                           int* __restrict__ cellid, int* __restrict__ rank) {
    int t = blockIdx.x * 256 + threadIdx.x;
    if (t >= NTOT) return;
    const float* p = xyz + (size_t)t * 3;
    float x = p[0], y = p[1], z = p[2];
    int cx = min(GD - 1, max(0, (int)floorf((x - ORGN) * INVH)));
    int cy = min(GD - 1, max(0, (int)floorf((y - ORGN) * INVH)));
    int cz = min(GD - 1, max(0, (int)floorf((z - ORGN) * INVH)));
    int gcell = (t >> 13) * NCELL + (cz * GD + cy) * GD + cx;
    rank[t] = atomicAdd(&cnt[gcell], 1);
    cellid[t] = gcell;
}

// -------- hierarchical exclusive scan of cnt[TOTC] -> offs[TOTC] (+rng int2) --------
__global__ __launch_bounds__(256) void scan_sums(const int* __restrict__ cnt, int* __restrict__ bsum) {
    __shared__ int red[256];
    int blk = blockIdx.x, t = threadIdx.x;
    int i0 = blk * SCAN_CHUNK + t * 4;
    int s = 0;
    if (i0 + 3 < TOTC) {
        int4 v = *(const int4*)(cnt + i0);
        s = v.x + v.y + v.z + v.w;
    } else {
        for (int j = 0; j < 4; ++j) if (i0 + j < TOTC) s += cnt[i0 + j];
    }
    red[t] = s;
    __syncthreads();
    for (int d = 128; d > 0; d >>= 1) {
        if (t < d) red[t] += red[t + d];
        __syncthreads();
    }
    if (t == 0) bsum[blk] = red[0];
}

__global__ __launch_bounds__(512) void scan_top(const int* __restrict__ bsum, int* __restrict__ bpre) {
    __shared__ int ps[512];
    int t = threadIdx.x;
    int v = (t < NBLK_SCAN) ? bsum[t] : 0;
    ps[t] = v;
    __syncthreads();
    for (int d = 1; d < 512; d <<= 1) {
        int u = 0;
        if (t >= d) u = ps[t - d];
        __syncthreads();
        ps[t] += u;
        __syncthreads();
    }
    if (t < NBLK_SCAN) bpre[t] = ps[t] - v;   // exclusive
}

__global__ __launch_bounds__(256) void scan_write(const int* __restrict__ cnt, const int* __restrict__ bpre,
                                                  int* __restrict__ offs, int2* __restrict__ rng) {
    __shared__ int ps[256];
    int blk = blockIdx.x, t = threadIdx.x;
    int i0 = blk * SCAN_CHUNK + t * 4;
    int a = 0, b = 0, c = 0, d = 0;
    if (i0 + 3 < TOTC) {
        int4 v = *(const int4*)(cnt + i0);
        a = v.x; b = v.y; c = v.z; d = v.w;
    } else {
        if (i0 + 0 < TOTC) a = cnt[i0 + 0];
        if (i0 + 1 < TOTC) b = cnt[i0 + 1];
        if (i0 + 2 < TOTC) c = cnt[i0 + 2];
        if (i0 + 3 < TOTC) d = cnt[i0 + 3];
    }
    int s = a + b + c + d;
    ps[t] = s;
    __syncthreads();
    for (int dd = 1; dd < 256; dd <<= 1) {
        int u = 0;
        if (t >= dd) u = ps[t - dd];
        __syncthreads();
        ps[t] += u;
        __syncthreads();
    }
    int base = bpre[blk] + ps[t] - s;
    if (i0 + 3 < TOTC) {
        offs[i0 + 0] = base;
        offs[i0 + 1] = base + a;
        offs[i0 + 2] = base + a + b;
        offs[i0 + 3] = base + a + b + c;
        *(int4*)(rng + i0)     = make_int4(base, base + a, base + a, base + a + b);
        *(int4*)(rng + i0 + 2) = make_int4(base + a + b, base + a + b + c,
                                           base + a + b + c, base + s);
    } else {
        if (i0 + 0 < TOTC) { offs[i0 + 0] = base;             rng[i0 + 0] = make_int2(base, base + a); }
        if (i0 + 1 < TOTC) { offs[i0 + 1] = base + a;         rng[i0 + 1] = make_int2(base + a, base + a + b); }
        if (i0 + 2 < TOTC) { offs[i0 + 2] = base + a + b;     rng[i0 + 2] = make_int2(base + a + b, base + a + b + c); }
        if (i0 + 3 < TOTC) { offs[i0 + 3] = base + a + b + c; rng[i0 + 3] = make_int2(base + a + b + c, base + s); }
    }
}

__global__ void scatter_k(const float* __restrict__ xyz, const int* __restrict__ cellid,
                          const int* __restrict__ rank, const int* __restrict__ offs,
                          float4* __restrict__ spos) {
    int t = blockIdx.x * 256 + threadIdx.x;
    if (t >= NTOT) return;
    const float* p = xyz + (size_t)t * 3;
    float x = p[0], y = p[1], z = p[2];
    int pos = offs[cellid[t]] + rank[t];
    spos[pos] = make_float4(x, y, z, __int_as_float(t & (NPTS - 1)));
}

// ---------------- exact KNN: one wave per query ----------------
// R14 = R11 (best measured) + a cheap margin(1) first rung.
// Certificate (R11-proven, any RB with mfin = margin0 + RB*h): margin0 <= every
// face distance, so any cell with |dy| or |dz| > RB has min-dist >= face_dist +
// RB*h >= mfin; the 1e-4 key shave excludes the boundary. x is unrestricted
// (row range from sqrt). Phases: A ball(margin(1)) [~9 rows, resolves dense
// ~70%], B reset+ball(margin(2)), C reset+ball(margin(4)), else ladder brute.
// Selection: rank-count over certified-complete sel (R8/R10-proven).
__global__ __launch_bounds__(64) void knn_kernel(const float4* __restrict__ spos,
                                                 const int2* __restrict__ rng,
                                                 int* __restrict__ knn,
                                                 float* __restrict__ spatial) {
    __shared__ __align__(16) unsigned long long sel[SEL_CAP];  // 8 KB
    __shared__ __align__(16) unsigned long long sel2[512];     // 4 KB
    int lane = threadIdx.x;
    int bid  = blockIdx.x;
    int s = (bid & 7) * (NTOT / 8) + (bid >> 3);   // XCD-chunked swizzle
    float4 q = spos[s];
    float qx = q.x, qy = q.y, qz = q.z;
    float qxx = sumsq3(qx, qy, qz);
    int b  = s >> 13;
    int nq = __float_as_int(q.w);
    int cx = min(GD - 1, max(0, (int)floorf((qx - ORGN) * INVH)));
    int cy = min(GD - 1, max(0, (int)floorf((qy - ORGN) * INVH)));
    int cz = min(GD - 1, max(0, (int)floorf((qz - ORGN) * INVH)));
    const int2* rg = rng + b * NCELL;

    float mlx = qx - (ORGN + (float)cx * HCELL);
    float mhx = (ORGN + (float)(cx + 1) * HCELL) - qx;
    float mly = qy - (ORGN + (float)cy * HCELL);
    float mhy = (ORGN + (float)(cy + 1) * HCELL) - qy;
    float mlz = qz - (ORGN + (float)cz * HCELL);
    float mhz = (ORGN + (float)(cz + 1) * HCELL) - qz;
    float margin0 = fminf(fminf(fminf(mlx, mhx), fminf(mly, mhy)), fminf(mlz, mhz));

    int tot = 0, ovf = 0;

    // scan all cells intersecting ball(mfin); append keys < tkfin to sel.
    auto scan_ball = [&](int RB, float mfin, unsigned long long tkfin) {
        if (mfin <= 0.f) return;
        float mfin2 = mfin * mfin;
        int L = 2 * RB + 1, nrows = L * L;
        for (int r0 = 0; r0 < nrows; r0 += 64) {
            int nr = min(64, nrows - r0);
            int rr = r0 + lane;
            int num = 0, start = 0;
            if (rr < nrows) {
                int dzr = rr / L - RB, dyr = rr % L - RB;
                int zc = cz + dzr, yc = cy + dyr;
                if ((unsigned)zc < GD && (unsigned)yc < GD) {
                    float ylo = ORGN + (float)yc * HCELL;
                    float zlo = ORGN + (float)zc * HCELL;
                    float dyl = fmaxf(fmaxf(ylo - qy, qy - (ylo + HCELL)), 0.f);
                    float dzl = fmaxf(fmaxf(zlo - qz, qz - (zlo + HCELL)), 0.f);
                    float rem = mfin2 - dyl * dyl - dzl * dzl;
                    if (rem > -1e-4f) {
                        float xh = sqrtf(fmaxf(rem, 0.f)) + 1e-3f;  // cushion: include boundary cells
                        int xlo = max(0, (int)floorf((qx - xh - ORGN) * INVH));
                        int xhi = min(GD - 1, (int)floorf((qx + xh - ORGN) * INVH));
                        if (xlo <= xhi) {
                            int rowb = (zc * GD + yc) * GD;
                            start = rg[rowb + xlo].x;
                            num   = rg[rowb + xhi].y - start;
                        }
                    }
                }
            }
            int inc = wave_scan_incl(num, lane);
            int ctot = __shfl(inc, 63, 64);
            if (ctot == 0) continue;
            int excl = inc - num;
            // expand candidate index -> slot via 6-step shfl lower_bound, then gather
            auto eg = [&](int base, int& sv, float4& pv, bool& vld) {
                int t = base + lane;
                vld = t < ctot;
                int tc = vld ? t : (ctot - 1);
                int lo = 0, hi = nr - 1;
                #pragma unroll
                for (int st = 0; st < 6; ++st) {
                    int mid = (lo + hi + 1) >> 1;
                    int e = __shfl(excl, mid, 64);
                    bool g = (e <= tc);
                    lo = g ? mid : lo;
                    hi = g ? hi : (mid - 1);
                }
                sv = __shfl(start, lo, 64) + (tc - __shfl(excl, lo, 64));
                pv = spos[sv];
            };
            int s0; float4 p0; bool v0;
            eg(0, s0, p0, v0);
            for (int base = 0; base < ctot; base += 64) {
                int s1 = 0; float4 p1 = p0; bool v1 = false;
                if (base + 64 < ctot) eg(base + 64, s1, p1, v1);   // prefetch next chunk
                float d = pdist4(qx, qy, qz, qxx, p0.x, p0.y, p0.z);
                unsigned long long key = ((unsigned long long)fkey(d) << 27)
                                       | ((unsigned long long)(unsigned)__float_as_int(p0.w) << 14)
                                       | (unsigned)s0;
                bool pass = v0 && (key < tkfin);
                unsigned long long mk = __ballot(pass);
                int cnum = (int)__popcll(mk);
                if (tot + cnum > SEL_CAP) { ovf = 1; return; }
                if (pass) sel[tot + (int)__popcll(mk & ((1ULL << lane) - 1ULL))] = key;
                tot += cnum;
                s0 = s1; p0 = p1; v0 = v1;
            }
        }
    };

    auto count_below = [&](unsigned long long tk) {
        int c = 0;
        for (int t0 = 0; t0 < tot; t0 += 64) {
            int tt = t0 + lane;
            if (tt < tot) c += (sel[tt] < tk) ? 1 : 0;
        }
        for (int o = 32; o > 0; o >>= 1) c += __shfl_xor(c, o, 64);
        return c;
    };

    unsigned long long tkey_sel = ~0ULL;
    int csel = 0;
    bool have = false;

    // ---- phase A: ball(margin(1)) — cheap first rung ----
    float mfinA = margin0 + HCELL;
    unsigned long long tkfA = (mfinA > 0.f) ? tkmake(mfinA) : 0ULL;
    if (tkfA) scan_ball(1, mfinA, tkfA);
    if (!ovf && tot >= 16) {
        if (margin0 > 0.f) {
            unsigned long long tk0 = tkmake(margin0);
            int c0 = count_below(tk0);
            if (c0 >= 16) { tkey_sel = tk0; csel = c0; have = true; }
        }
        if (!have) { tkey_sel = ~0ULL; csel = tot; have = true; }   // all of sel (< margin(1))
    }

    if (!have && !ovf) {
        // ---- phase B: reset + rescan ball(margin(RSTART)) ----
        tot = 0;
        float mfin1 = margin0 + (float)RSTART * HCELL;
        unsigned long long tkf1 = (mfin1 > 0.f) ? tkmake(mfin1) : 0ULL;
        if (tkf1) scan_ball(RSTART, mfin1, tkf1);
        if (!ovf && tot >= 16) {
            float mA = margin0 + 1.0f * HCELL;
            if (mA > 0.f) {
                unsigned long long tkA = tkmake(mA);
                int cA = count_below(tkA);
                if (cA >= 16) { tkey_sel = tkA; csel = cA; have = true; }
            }
            if (!have) { tkey_sel = ~0ULL; csel = tot; have = true; }
        }
    }
    if (!have && !ovf) {
        // ---- phase C: reset + rescan ball(margin(RESC)) ----
        tot = 0;
        float mfin4 = margin0 + (float)RESC * HCELL;
        unsigned long long tkf4 = (mfin4 > 0.f) ? tkmake(mfin4) : 0ULL;
        if (tkf4) scan_ball(RESC, mfin4, tkf4);
        if (!ovf && tot >= 16) {
            float mB = margin0 + (float)(RESC - 1) * HCELL;
            if (mB > 0.f) {
                unsigned long long tkB = tkmake(mB);
                int cB = count_below(tkB);
                if (cB >= 16) { tkey_sel = tkB; csel = cB; have = true; }
            }
            if (!have) { tkey_sel = ~0ULL; csel = tot; have = true; }
        }
    }

    if (!have) {
        // ---- two-pass ladder brute over all NPTS of this batch (R10-proven) ----
        const float LADR[16] = {0.35f, 0.4725f, 0.637875f, 0.86113125f,
                                1.1625272f, 1.5694117f, 2.1187058f, 2.8602529f,
                                3.8613414f, 5.2128109f, 7.0372947f, 9.5003478f,
                                12.825470f, 17.314384f, 23.374418f, 31.555464f};
        int sbase = b << 13;
        int cc[16];
        #pragma unroll
        for (int k = 0; k < 16; ++k) cc[k] = 0;
        for (int i0 = 0; i0 < NPTS; i0 += 64) {
            float4 p = spos[sbase + i0 + lane];
            float d = pdist4(qx, qy, qz, qxx, p.x, p.y, p.z);
            #pragma unroll
            for (int k = 0; k < 16; ++k) cc[k] += (d < LADR[k] * LADR[k]) ? 1 : 0;
        }
        #pragma unroll
        for (int k = 0; k < 16; ++k)
            for (int o = 32; o > 0; o >>= 1) cc[k] += __shfl_xor(cc[k], o, 64);
        float Tq = LADR[15] * LADR[15]; int cL = cc[15];
        #pragma unroll
        for (int k = 14; k >= 0; --k) if (cc[k] >= 16) { Tq = LADR[k] * LADR[k]; cL = cc[k]; }
        if (cL <= SEL_CAP) {
            tot = 0;
            for (int i0 = 0; i0 < NPTS; i0 += 64) {
                int idx = sbase + i0 + lane;
                float4 p = spos[idx];
                float d = pdist4(qx, qy, qz, qxx, p.x, p.y, p.z);
                bool pass = (d < Tq);
                unsigned long long key = ((unsigned long long)fkey(d) << 27)
                                       | ((unsigned long long)(unsigned)__float_as_int(p.w) << 14)
                                       | (unsigned)idx;
                unsigned long long mk = __ballot(pass);
                if (pass) sel[tot + (int)__popcll(mk & ((1ULL << lane) - 1ULL))] = key;
                tot += (int)__popcll(mk);
            }
            tkey_sel = ~0ULL;
            csel = tot;
        } else {
            // ultra-rare capacity fallback: per-lane top16 in sel region + 16-round extract
            unsigned long long* mybuf = sel + lane;   // element j at [j*64]
            unsigned long long minkey = ~0ULL, maxkey = 0;
            int nbuf = 0;
            for (int i = lane; i < NPTS; i += 64) {
                float4 p = spos[sbase + i];
                float d = pdist4(qx, qy, qz, qxx, p.x, p.y, p.z);
                unsigned long long key = ((unsigned long long)fkey(d) << 27)
                                       | ((unsigned long long)(unsigned)__float_as_int(p.w) << 14)
                                       | (unsigned)(sbase + i);
                if (nbuf < 16) {
                    mybuf[(size_t)nbuf * 64] = key;
                    ++nbuf;
                    minkey = (key < minkey) ? key : minkey;
                    maxkey = (key > maxkey) ? key : maxkey;
                } else if (key < maxkey) {
                    unsigned long long vmax = 0, v2 = 0;
                    int pmax = 0;
                    #pragma unroll
                    for (int j = 0; j < 16; ++j) {
                        unsigned long long v = mybuf[(size_t)j * 64];
                        if (v > vmax) { v2 = vmax; vmax = v; pmax = j; }
                        else if (v > v2) { v2 = v; }
                    }
                    mybuf[(size_t)pmax * 64] = key;
                    maxkey = (key > v2) ? key : v2;
                    minkey = (key < minkey) ? key : minkey;
                }
            }
            unsigned long long keep = ~0ULL;
            for (int k = 0; k < 16; ++k) {
                unsigned long long m = minkey;
                for (int o = 32; o > 0; o >>= 1) {
                    unsigned long long pv = shflx64(m, o);
                    m = (pv < m) ? pv : m;
                }
                unsigned long long bal = __ballot(minkey == m);
                int wl = __ffsll((long long)bal) - 1;
                if (lane == wl) {
                    int pos = 0;
                    for (int j = 0; j < nbuf; ++j) if (mybuf[(size_t)j * 64] == m) pos = j;
                    --nbuf;
                    mybuf[(size_t)pos * 64] = mybuf[(size_t)nbuf * 64];
                    unsigned long long nm = ~0ULL;
                    for (int j = 0; j < nbuf; ++j) {
                        unsigned long long v = mybuf[(size_t)j * 64];
                        nm = (v < nm) ? v : nm;
                    }
                    minkey = nm;
                }
                if (lane == k) keep = m;
            }
            float rx = 0.f, ry = 0.f, rz = 0.f, rd = 0.f;
            if (lane < 16) {
                int sp = (int)(keep & 0x3FFFu);
                int oi = (int)((keep >> 14) & 0x1FFFu);
                float4 p = spos[sp];
                rx = p.x - qx; ry = p.y - qy; rz = p.z - qz;
                rd = sqrtf(__fadd_rn(__fadd_rn(__fmul_rn(rx, rx), __fmul_rn(ry, ry)), __fmul_rn(rz, rz)));
                knn[(((size_t)b << 13) + nq) * 16 + lane] = oi;
            }
            for (int o = 8; o > 0; o >>= 1) {
                rx += __shfl_xor(rx, o, 64);
                ry += __shfl_xor(ry, o, 64);
                rz += __shfl_xor(rz, o, 64);
                rd += __shfl_xor(rd, o, 64);
            }
            if (lane == 0) {
                const float inv16 = 0.0625f;
                spatial[((size_t)b * 4 + 0) * NPTS + nq] = rx * inv16;
                spatial[((size_t)b * 4 + 1) * NPTS + nq] = ry * inv16;
                spatial[((size_t)b * 4 + 2) * NPTS + nq] = rz * inv16;
                spatial[((size_t)b * 4 + 3) * NPTS + nq] = rd * inv16;
            }
            return;
        }
    }

    // -------- shared selection: compact keys < tkey_sel, then rank-count --------
    const unsigned long long* src = sel;
    int m = tot;
    if (tkey_sel != ~0ULL && csel <= 512) {
        int w = 0;
        for (int t0 = 0; t0 < tot; t0 += 64) {
            int tt = t0 + lane;
            unsigned long long v = (tt < tot) ? sel[tt] : ~0ULL;
            bool pass = (tt < tot) && (v < tkey_sel);
            unsigned long long mk = __ballot(pass);
            if (pass) sel2[w + (int)__popcll(mk & ((1ULL << lane) - 1ULL))] = v;
            w += (int)__popcll(mk);
        }
        asm volatile("s_waitcnt lgkmcnt(0)" ::: "memory");
        __builtin_amdgcn_sched_barrier(0);
        src = sel2; m = w;
        tkey_sel = ~0ULL;   // compacted list is fully qualified
    }
    float rxs = 0.f, rys = 0.f, rzs = 0.f, rds = 0.f;
    for (int t0 = 0; t0 < m; t0 += 64) {
        int tt = t0 + lane;
        if (tt < m) {
            unsigned long long kt = src[tt];
            if (kt < tkey_sel) {
                int rr = 0;
                for (int j = 0; j < m; ++j) rr += (src[j] < kt) ? 1 : 0;   // broadcast reads
                if (rr < 16) {
                    int sp = (int)(kt & 0x3FFFu);
                    int oi = (int)((kt >> 14) & 0x1FFFu);
                    float4 p = spos[sp];
                    float dx = p.x - qx, dy = p.y - qy, dz = p.z - qz;
                    float dl = sqrtf(__fadd_rn(__fadd_rn(__fmul_rn(dx, dx), __fmul_rn(dy, dy)), __fmul_rn(dz, dz)));
                    knn[(((size_t)b << 13) + nq) * 16 + rr] = oi;
                    rxs += dx; rys += dy; rzs += dz; rds += dl;
                }
            }
        }
    }
    for (int o = 32; o > 0; o >>= 1) {
        rxs += __shfl_xor(rxs, o, 64);
        rys += __shfl_xor(rys, o, 64);
        rzs += __shfl_xor(rzs, o, 64);
        rds += __shfl_xor(rds, o, 64);
    }
    if (lane == 0) {
        const float inv16 = 0.0625f;
        spatial[((size_t)b * 4 + 0) * NPTS + nq] = rxs * inv16;
        spatial[((size_t)b * 4 + 1) * NPTS + nq] = rys * inv16;
        spatial[((size_t)b * 4 + 2) * NPTS + nq] = rzs * inv16;
        spatial[((size_t)b * 4 + 3) * NPTS + nq] = rds * inv16;
    }
}

// ---------------- x[B,C,N] -> xT[B,N,C] ----------------
__global__ void transpose_k(const float* __restrict__ x, float* __restrict__ xT) {
    __shared__ float tl[32][33];
    int b = blockIdx.z;
    int n0 = blockIdx.x * 32, c0 = blockIdx.y * 32;
    int tx = threadIdx.x, ty = threadIdx.y;
    const float* xb = x + (size_t)b * 128 * NN;
    float* xtb = xT + (size_t)b * NN * 128;
    for (int i = 0; i < 32; i += 8) tl[ty + i][tx] = xb[(size_t)(c0 + ty + i) * NN + n0 + tx];
    __syncthreads();
    for (int i = 0; i < 32; i += 8) xtb[(size_t)(n0 + ty + i) * 128 + c0 + tx] = tl[tx][ty + i];
}

// ---------------- max_k(x[:,idx_k]) - x  -> md[B,128,N] ----------------
__global__ __launch_bounds__(256) void md_k(const float* __restrict__ xT,
                                            const int* __restrict__ knn,
                                            float* __restrict__ md) {
    __shared__ int ki[8][16];
    __shared__ float smd[8][132];
    int b = blockIdx.y;
    int n0 = blockIdx.x * 8;
    int tid = threadIdx.x;
    if (tid < 128) ki[tid >> 4][tid & 15] = knn[(((size_t)b << 13) + n0 + (tid >> 4)) * 16 + (tid & 15)];
    __syncthreads();
    int nl = tid >> 5;
    int c4 = (tid & 31) * 4;
    const float* xb = xT + (size_t)b * NPTS * 128;
    float4 m = make_float4(-3.0e38f, -3.0e38f, -3.0e38f, -3.0e38f);
    #pragma unroll
    for (int k = 0; k < 16; ++k) {
        const float4 g = *(const float4*)(xb + (size_t)ki[nl][k] * 128 + c4);
        m.x = fmaxf(m.x, g.x); m.y = fmaxf(m.y, g.y); m.z = fmaxf(m.z, g.z); m.w = fmaxf(m.w, g.w);
    }
    const float4 own = *(const float4*)(xb + (size_t)(n0 + nl) * 128 + c4);
    m.x -= own.x; m.y -= own.y; m.z -= own.z; m.w -= own.w;
    *(float4*)(&smd[nl][c4]) = m;
    __syncthreads();
    for (int r = 0; r < 4; ++r) {
        int c = (tid >> 3) + 32 * r;
        int n2 = tid & 7;
        md[((size_t)b * 128 + c) * NN + n0 + n2] = smd[n2][c];
    }
}

// ---------------- fold conv-bias + BN into per-channel scale/shift ----------------
__global__ void prep_k(const float* bb1, const float* g1, const float* be1, const float* m1, const float* v1,
                       const float* bb2, const float* g2, const float* be2, const float* m2, const float* v2,
                       const float* sb1, const float* gs,  const float* bes, const float* ms, const float* vs,
                       const float* sb2,
                       const float* ab1, const float* ga,  const float* bea, const float* ma, const float* va,
                       const float* ab2, float* sc) {
    int t = threadIdx.x;
    if (t < 128) {
        float i1 = g1[t] / sqrtf(v1[t] + 1e-5f);
        sc[t] = i1;        sc[128 + t] = bb1[t] * i1 + be1[t] - m1[t] * i1;
        float i2 = g2[t] / sqrtf(v2[t] + 1e-5f);
        sc[256 + t] = i2;  sc[384 + t] = bb2[t] * i2 + be2[t] - m2[t] * i2;
        sc[832 + t] = 1.0f; sc[960 + t] = ab2[t];
    }
    if (t < 32) {
        float is = gs[t] / sqrtf(vs[t] + 1e-5f);
        sc[512 + t] = is;  sc[544 + t] = sb1[t] * is + bes[t] - ms[t] * is;
    }
    if (t < 64) {
        sc[576 + t] = 1.0f; sc[640 + t] = sb2[t];
        float ia = ga[t] / sqrtf(va[t] + 1e-5f);
        sc[704 + t] = ia;  sc[768 + t] = ab1[t] * ia + bea[t] - ma[t] * ia;
    }
}

// ---------------- generic 1x1-conv (+folded BN, activation) ----------------
// ACT: 0=none, 1=relu, 2=sigmoid + fused "dout = x + y2*attn"
template <int O, int K, int TILE_N, int SPLIT, int ACT>
__global__ __launch_bounds__(256) void conv_bn(const float* __restrict__ srcA,
                                               const float* __restrict__ srcB,
                                               const float* __restrict__ W,
                                               const float* __restrict__ scale,
                                               const float* __restrict__ shift,
                                               float* __restrict__ out,
                                               const float* __restrict__ resx,
                                               const float* __restrict__ y2,
                                               float* __restrict__ dout) {
    constexpr int KC  = (K < 64) ? K : 64;
    constexpr int NT4 = TILE_N / 4;
    constexpr int O4  = O / 4;
    static_assert(NT4 * O4 == 256, "thread mapping");
    __shared__ float wT[KC][O + 4];
    __shared__ float inT[KC][TILE_N];
    int tid = threadIdx.x;
    int b = blockIdx.z;
    int n0 = blockIdx.x * TILE_N;
    int n_thr = tid % NT4;          // n fastest -> coalesced stores
    int o_thr = tid / NT4;
    float acc[4][4] = {{0.f, 0.f, 0.f, 0.f}, {0.f, 0.f, 0.f, 0.f}, {0.f, 0.f, 0.f, 0.f}, {0.f, 0.f, 0.f, 0.f}};

    for (int k0 = 0; k0 < K; k0 += KC) {
        for (int idx = tid; idx < KC * O; idx += 256) {
            int cc = idx % KC;
            int o  = idx / KC;
            wT[cc][o] = W[(size_t)o * K + k0 + cc];
        }
        for (int idx = tid; idx < KC * NT4; idx += 256) {
            int cc = idx / NT4;
            int nf = idx % NT4;
            int cg = k0 + cc;
            const float* src = (cg < SPLIT)
                ? (srcA + ((size_t)b * SPLIT + cg) * NN)
                : (srcB + ((size_t)b * (K - SPLIT) + (cg - SPLIT)) * NN);
            *(float4*)(&inT[cc][nf * 4]) = *(const float4*)(src + n0 + nf * 4);
        }
        __syncthreads();
        #pragma unroll 8
        for (int c = 0; c < KC; ++c) {
            float4 wv = *(const float4*)(&wT[c][o_thr * 4]);
            float4 iv = *(const float4*)(&inT[c][n_thr * 4]);
            acc[0][0] = fmaf(wv.x, iv.x, acc[0][0]); acc[0][1] = fmaf(wv.x, iv.y, acc[0][1]);
            acc[0][2] = fmaf(wv.x, iv.z, acc[0][2]); acc[0][3] = fmaf(wv.x, iv.w, acc[0][3]);
            acc[1][0] = fmaf(wv.y, iv.x, acc[1][0]); acc[1][1] = fmaf(wv.y, iv.y, acc[1][1]);
            acc[1][2] = fmaf(wv.y, iv.z, acc[1][2]); acc[1][3] = fmaf(wv.y, iv.w, acc[1][3]);
            acc[2][0] = fmaf(wv.z, iv.x, acc[2][0]); acc[2][1] = fmaf(wv.z, iv.y, acc[2][1]);
            acc[2][2] = fmaf(wv.z, iv.z, acc[2][2]); acc[2][3] = fmaf(wv.z, iv.w, acc[2][3]);
            acc[3][0] = fmaf(wv.w, iv.x, acc[3][0]); acc[3][1] = fmaf(wv.w, iv.y, acc[3][1]);
            acc[3][2] = fmaf(wv.w, iv.z, acc[3][2]); acc[3][3] = fmaf(wv.w, iv.w, acc[3][3]);
        }
        __syncthreads();
    }
    #pragma unroll
    for (int j = 0; j < 4; ++j) {
        int o = o_thr * 4 + j;
        float scv = scale[o], shv = shift[o];
        float4 v;
        v.x = fmaf(acc[j][0], scv, shv);
        v.y = fmaf(acc[j][1], scv, shv);
        v.z = fmaf(acc[j][2], scv, shv);
        v.w = fmaf(acc[j][3], scv, shv);
        size_t obase = ((size_t)b * O + o) * NN + n0 + n_thr * 4;
        if (ACT == 1) {
            v.x = fmaxf(v.x, 0.f); v.y = fmaxf(v.y, 0.f); v.z = fmaxf(v.z, 0.f); v.w = fmaxf(v.w, 0.f);
            *(float4*)(out + obase) = v;
        } else if (ACT == 2) {
            float4 xr = *(const float4*)(resx + obase);
            float4 yr = *(const float4*)(y2 + obase);
            v.x = xr.x + yr.x / (1.f + __expf(-v.x));
            v.y = xr.y + yr.y / (1.f + __expf(-v.y));
            v.z = xr.z + yr.z / (1.f + __expf(-v.z));
            v.w = xr.w + yr.w / (1.f + __expf(-v.w));
            *(float4*)(dout + obase) = v;
        } else {
            *(float4*)(out + obase) = v;
        }
    }
}

extern "C" void kernel_launch(void* const* d_in, const int* in_sizes, int n_in,
                              void* d_out, int out_size, void* d_ws, size_t ws_size,
                              hipStream_t stream) {
    (void)in_sizes; (void)n_in; (void)out_size; (void)ws_size;
    const float* x    = (const float*)d_in[0];
    const float* xyz  = (const float*)d_in[1];
    const float* bw1  = (const float*)d_in[2];
    const float* bb1  = (const float*)d_in[3];
    const float* bn1g = (const float*)d_in[4];
    const float* bn1b = (const float*)d_in[5];
    const float* bn1m = (const float*)d_in[6];
    const float* bn1v = (const float*)d_in[7];
    const float* bw2  = (const float*)d_in[8];
    const float* bb2  = (const float*)d_in[9];
    const float* bn2g = (const float*)d_in[10];
    const float* bn2b = (const float*)d_in[11];
    const float* bn2m = (const float*)d_in[12];
    const float* bn2v = (const float*)d_in[13];
    const float* sw1  = (const float*)d_in[14];
    const float* sb1  = (const float*)d_in[15];
    const float* sbng = (const float*)d_in[16];
    const float* sbnb = (const float*)d_in[17];
    const float* sbnm = (const float*)d_in[18];
    const float* sbnv = (const float*)d_in[19];
    const float* sw2  = (const float*)d_in[20];
    const float* sb2  = (const float*)d_in[21];
    const float* aw1  = (const float*)d_in[22];
    const float* ab1  = (const float*)d_in[23];
    const float* abng = (const float*)d_in[24];
    const float* abnb = (const float*)d_in[25];
    const float* abnm = (const float*)d_in[26];
    const float* abnv = (const float*)d_in[27];
    const float* aw2  = (const float*)d_in[28];
    const float* ab2  = (const float*)d_in[29];

    char* ws = (char*)d_ws;
    int*    cnt    = (int*)(ws + OFF_CNT);
    int*    offs   = (int*)(ws + OFF_OFFS);
    int*    cellid = (int*)(ws + OFF_CELLID);
    int*    rank   = (int*)(ws + OFF_RANK);
    float4* spos   = (float4*)(ws + OFF_SPOS);
    int*    knn    = (int*)(ws + OFF_KNN);
    float*  spat   = (float*)(ws + OFF_SPATIAL);
    float*  xT     = (float*)(ws + OFF_XT);
    float*  md     = (float*)(ws + OFF_MD);
    float*  s1b    = (float*)(ws + OFF_S1);
    float*  sfb    = (float*)(ws + OFF_SF);
    float*  y1b    = (float*)(ws + OFF_Y1);
    float*  y2b    = (float*)(ws + OFF_Y2);
    float*  a1b    = (float*)(ws + OFF_A1);
    float*  sc     = (float*)(ws + OFF_SC);
    int*    bsum   = (int*)(ws + OFF_BSUM);
    int*    bpre   = (int*)(ws + OFF_BPRE);
    int2*   rng    = (int2*)(ws + OFF_RNG);
    float*  dout   = (float*)d_out;

    hipMemsetAsync(cnt, 0, (size_t)TOTC * 4, stream);
    cell_build<<<dim3((NTOT + 255) / 256), 256, 0, stream>>>(xyz, cnt, cellid, rank);
    scan_sums<<<dim3(NBLK_SCAN), 256, 0, stream>>>(cnt, bsum);
    scan_top<<<dim3(1), 512, 0, stream>>>(bsum, bpre);
    scan_write<<<dim3(NBLK_SCAN), 256, 0, stream>>>(cnt, bpre, offs, rng);
    scatter_k<<<dim3((NTOT + 255) / 256), 256, 0, stream>>>(xyz, cellid, rank, offs, spos);
    knn_kernel<<<dim3(NTOT), 64, 0, stream>>>(spos, rng, knn, spat);
    transpose_k<<<dim3(NPTS / 32, 128 / 32, NB), dim3(32, 8), 0, stream>>>(x, xT);
    md_k<<<dim3(NPTS / 8, NB), 256, 0, stream>>>(xT, knn, md);
    prep_k<<<1, 128, 0, stream>>>(bb1, bn1g, bn1b, bn1m, bn1v,
                                  bb2, bn2g, bn2b, bn2m, bn2v,
                                  sb1, sbng, sbnb, sbnm, sbnv,
                                  sb2,
                                  ab1, abng, abnb, abnm, abnv,
                                  ab2, sc);
    // spatial MLP: 4->32 (bn,relu), 32->64
    conv_bn<32, 4, 128, 4, 1><<<dim3(NPTS / 128, 1, NB), 256, 0, stream>>>(
        spat, spat, sw1, sc + 512, sc + 544, s1b, nullptr, nullptr, nullptr);
    conv_bn<64, 32, 64, 32, 0><<<dim3(NPTS / 64, 1, NB), 256, 0, stream>>>(
        s1b, s1b, sw2, sc + 576, sc + 640, sfb, nullptr, nullptr, nullptr);
    // boundary net: [x;md] 256->128 (bn,relu), 128->128 (bn,relu)
    conv_bn<128, 256, 32, 128, 1><<<dim3(NPTS / 32, 1, NB), 256, 0, stream>>>(
        x, md, bw1, sc + 0, sc + 128, y1b, nullptr, nullptr, nullptr);
    conv_bn<128, 128, 32, 128, 1><<<dim3(NPTS / 32, 1, NB), 256, 0, stream>>>(
        y1b, y1b, bw2, sc + 256, sc + 384, y2b, nullptr, nullptr, nullptr);
    // attention: [x;sfeat] 192->64 (bn,relu), 64->128 sigmoid + final fuse
    conv_bn<64, 192, 64, 128, 1><<<dim3(NPTS / 64, 1, NB), 256, 0, stream>>>(
        x, sfb, aw1, sc + 704, sc + 768, a1b, nullptr, nullptr, nullptr);
    conv_bn<128, 64, 32, 64, 2><<<dim3(NPTS / 32, 1, NB), 256, 0, stream>>>(
        a1b, a1b, aw2, sc + 832, sc + 960, dout, x, y2b, dout);
}

// Round 9
// 321.593 us; speedup vs baseline: 4.3439x; 1.0252x over previous
//
#include <hip/hip_runtime.h>
#include <math.h>

#define NPTS  8192
#define NB    2
#define NTOT  (NPTS*NB)
#define GD    60
#define NCELL (GD*GD*GD)
#define TOTC  (NB*NCELL)
#define HCELL 0.2f
#define INVH  5.0f
#define ORGN  (-6.0f)
#define NN    8192
#define SCAN_CHUNK 1024
#define NBLK_SCAN  ((TOTC + SCAN_CHUNK - 1) / SCAN_CHUNK)
#define RSTART    2    // phase-1 ball radius = margin(RSTART)
#define RESC      4    // escalation ball radius = margin(RESC)
#define SEL_CAP  1024  // appended-key list (u64, 8KB)

// ---------------- workspace layout (bytes) ----------------
#define OFF_CNT     ((size_t)0)
#define OFF_OFFS    (OFF_CNT    + (size_t)TOTC*4)
#define OFF_CELLID  (OFF_OFFS   + (size_t)TOTC*4)
#define OFF_RANK    (OFF_CELLID + (size_t)NTOT*4)
#define OFF_SPOS    (OFF_RANK   + (size_t)NTOT*4)          // float4 * NTOT (w = origidx bits)
#define OFF_KNN     (OFF_SPOS   + (size_t)NTOT*16)         // int * NTOT*16
#define OFF_SPATIAL (OFF_KNN    + (size_t)NTOT*16*4)       // [B,4,N]
#define OFF_XT      (OFF_SPATIAL+ (size_t)NB*4*NPTS*4)     // [B,N,128]
#define OFF_MD      (OFF_XT     + (size_t)NB*128*NPTS*4)   // [B,128,N]
#define OFF_S1      (OFF_MD     + (size_t)NB*128*NPTS*4)   // [B,32,N]
#define OFF_SF      (OFF_S1     + (size_t)NB*32*NPTS*4)    // [B,64,N]
#define OFF_Y1      (OFF_SF     + (size_t)NB*64*NPTS*4)    // [B,128,N] (unused after fusion)
#define OFF_Y2      (OFF_Y1     + (size_t)NB*128*NPTS*4)   // [B,128,N]
#define OFF_A1      (OFF_Y2     + (size_t)NB*128*NPTS*4)   // [B,64,N]  (unused after fusion)
#define OFF_SC      (OFF_A1     + (size_t)NB*64*NPTS*4)    // 1088 floats
#define OFF_BSUM    (OFF_SC     + (size_t)1088*4)          // NBLK_SCAN ints
#define OFF_BPRE    (OFF_BSUM   + (size_t)NBLK_SCAN*4)     // NBLK_SCAN ints
#define OFF_RNG     (((OFF_BPRE + (size_t)NBLK_SCAN*4) + 15) & ~(size_t)15)  // int2 * TOTC

// Replicate reference arithmetic exactly (no fma contraction).
static __device__ __forceinline__ float sumsq3(float x, float y, float z) {
    return __fadd_rn(__fadd_rn(__fmul_rn(x, x), __fmul_rn(y, y)), __fmul_rn(z, z));
}
static __device__ __forceinline__ float pdist4(float qx, float qy, float qz, float qxx,
                                               float px, float py, float pz) {
    float pxx = sumsq3(px, py, pz);
    float dot = __fadd_rn(__fadd_rn(__fmul_rn(qx, px), __fmul_rn(qy, py)), __fmul_rn(qz, pz));
    return __fsub_rn(__fadd_rn(qxx, pxx), __fadd_rn(dot, dot));
}
// monotone unsigned key for float (handles tiny negative self-distance)
static __device__ __forceinline__ unsigned fkey(float f) {
    unsigned b = __float_as_uint(f);
    return b ^ ((unsigned)(((int)b) >> 31) | 0x80000000u);
}
static __device__ __forceinline__ unsigned long long shflx64(unsigned long long v, int m) {
    unsigned lo = __shfl_xor((unsigned)v, m, 64);
    unsigned hi = __shfl_xor((unsigned)(v >> 32), m, 64);
    return ((unsigned long long)hi << 32) | lo;
}
// inclusive wave prefix-sum (all 64 lanes active)
static __device__ __forceinline__ int wave_scan_incl(int v, int lane) {
    #pragma unroll
    for (int d = 1; d < 64; d <<= 1) {
        int u = __shfl_up(v, d, 64);
        v += (lane >= d) ? u : 0;
    }
    return v;
}
// key threshold from margin m (>0): all keys strictly below are certified-complete
static __device__ __forceinline__ unsigned long long tkmake(float m) {
    return ((unsigned long long)(fkey(__fsub_rn(__fmul_rn(m, m), 1e-4f)) + 1u)) << 27;
}

// ---------------- grid build ----------------
__global__ void cell_build(const float* __restrict__ xyz, int* __restrict__ cnt,
                           int* __restrict__ cellid, int* __restrict__ rank) {
    int t = blockIdx.x * 256 + threadIdx.x;
    if (t >= NTOT) return;
    const float* p = xyz + (size_t)t * 3;
    float x = p[0], y = p[1], z = p[2];
    int cx = min(GD - 1, max(0, (int)floorf((x - ORGN) * INVH)));
    int cy = min(GD - 1, max(0, (int)floorf((y - ORGN) * INVH)));
    int cz = min(GD - 1, max(0, (int)floorf((z - ORGN) * INVH)));
    int gcell = (t >> 13) * NCELL + (cz * GD + cy) * GD + cx;
    rank[t] = atomicAdd(&cnt[gcell], 1);
    cellid[t] = gcell;
}

// -------- hierarchical exclusive scan of cnt[TOTC] -> offs[TOTC] (+rng int2) --------
__global__ __launch_bounds__(256) void scan_sums(const int* __restrict__ cnt, int* __restrict__ bsum) {
    __shared__ int red[256];
    int blk = blockIdx.x, t = threadIdx.x;
    int i0 = blk * SCAN_CHUNK + t * 4;
    int s = 0;
    if (i0 + 3 < TOTC) {
        int4 v = *(const int4*)(cnt + i0);
        s = v.x + v.y + v.z + v.w;
    } else {
        for (int j = 0; j < 4; ++j) if (i0 + j < TOTC) s += cnt[i0 + j];
    }
    red[t] = s;
    __syncthreads();
    for (int d = 128; d > 0; d >>= 1) {
        if (t < d) red[t] += red[t + d];
        __syncthreads();
    }
    if (t == 0) bsum[blk] = red[0];
}

__global__ __launch_bounds__(512) void scan_top(const int* __restrict__ bsum, int* __restrict__ bpre) {
    __shared__ int ps[512];
    int t = threadIdx.x;
    int v = (t < NBLK_SCAN) ? bsum[t] : 0;
    ps[t] = v;
    __syncthreads();
    for (int d = 1; d < 512; d <<= 1) {
        int u = 0;
        if (t >= d) u = ps[t - d];
        __syncthreads();
        ps[t] += u;
        __syncthreads();
    }
    if (t < NBLK_SCAN) bpre[t] = ps[t] - v;   // exclusive
}

__global__ __launch_bounds__(256) void scan_write(const int* __restrict__ cnt, const int* __restrict__ bpre,
                                                  int* __restrict__ offs, int2* __restrict__ rng) {
    __shared__ int ps[256];
    int blk = blockIdx.x, t = threadIdx.x;
    int i0 = blk * SCAN_CHUNK + t * 4;
    int a = 0, b = 0, c = 0, d = 0;
    if (i0 + 3 < TOTC) {
        int4 v = *(const int4*)(cnt + i0);
        a = v.x; b = v.y; c = v.z; d = v.w;
    } else {
        if (i0 + 0 < TOTC) a = cnt[i0 + 0];
        if (i0 + 1 < TOTC) b = cnt[i0 + 1];
        if (i0 + 2 < TOTC) c = cnt[i0 + 2];
        if (i0 + 3 < TOTC) d = cnt[i0 + 3];
    }
    int s = a + b + c + d;
    ps[t] = s;
    __syncthreads();
    for (int dd = 1; dd < 256; dd <<= 1) {
        int u = 0;
        if (t >= dd) u = ps[t - dd];
        __syncthreads();
        ps[t] += u;
        __syncthreads();
    }
    int base = bpre[blk] + ps[t] - s;
    if (i0 + 3 < TOTC) {
        offs[i0 + 0] = base;
        offs[i0 + 1] = base + a;
        offs[i0 + 2] = base + a + b;
        offs[i0 + 3] = base + a + b + c;
        *(int4*)(rng + i0)     = make_int4(base, base + a, base + a, base + a + b);
        *(int4*)(rng + i0 + 2) = make_int4(base + a + b, base + a + b + c,
                                           base + a + b + c, base + s);
    } else {
        if (i0 + 0 < TOTC) { offs[i0 + 0] = base;             rng[i0 + 0] = make_int2(base, base + a); }
        if (i0 + 1 < TOTC) { offs[i0 + 1] = base + a;         rng[i0 + 1] = make_int2(base + a, base + a + b); }
        if (i0 + 2 < TOTC) { offs[i0 + 2] = base + a + b;     rng[i0 + 2] = make_int2(base + a + b, base + a + b + c); }
        if (i0 + 3 < TOTC) { offs[i0 + 3] = base + a + b + c; rng[i0 + 3] = make_int2(base + a + b + c, base + s); }
    }
}

__global__ void scatter_k(const float* __restrict__ xyz, const int* __restrict__ cellid,
                          const int* __restrict__ rank, const int* __restrict__ offs,
                          float4* __restrict__ spos) {
    int t = blockIdx.x * 256 + threadIdx.x;
    if (t >= NTOT) return;
    const float* p = xyz + (size_t)t * 3;
    float x = p[0], y = p[1], z = p[2];
    int pos = offs[cellid[t]] + rank[t];
    spos[pos] = make_float4(x, y, z, __int_as_float(t & (NPTS - 1)));
}

// ---------------- exact KNN: one wave per query (R11 verbatim — best measured) ----------------
// (a) ball-pruned rows; (b) tight append threshold margin(RSTART), escalation resets
// and rescans ball(margin(RESC)); (c) register binary-search expansion; rank-count
// selection over certified-complete sel; two-pass ladder brute tail.
__global__ __launch_bounds__(64) void knn_kernel(const float4* __restrict__ spos,
                                                 const int2* __restrict__ rng,
                                                 int* __restrict__ knn,
                                                 float* __restrict__ spatial) {
    __shared__ __align__(16) unsigned long long sel[SEL_CAP];  // 8 KB
    __shared__ __align__(16) unsigned long long sel2[512];     // 4 KB
    int lane = threadIdx.x;
    int bid  = blockIdx.x;
    int s = (bid & 7) * (NTOT / 8) + (bid >> 3);   // XCD-chunked swizzle
    float4 q = spos[s];
    float qx = q.x, qy = q.y, qz = q.z;
    float qxx = sumsq3(qx, qy, qz);
    int b  = s >> 13;
    int nq = __float_as_int(q.w);
    int cx = min(GD - 1, max(0, (int)floorf((qx - ORGN) * INVH)));
    int cy = min(GD - 1, max(0, (int)floorf((qy - ORGN) * INVH)));
    int cz = min(GD - 1, max(0, (int)floorf((qz - ORGN) * INVH)));
    const int2* rg = rng + b * NCELL;

    float mlx = qx - (ORGN + (float)cx * HCELL);
    float mhx = (ORGN + (float)(cx + 1) * HCELL) - qx;
    float mly = qy - (ORGN + (float)cy * HCELL);
    float mhy = (ORGN + (float)(cy + 1) * HCELL) - qy;
    float mlz = qz - (ORGN + (float)cz * HCELL);
    float mhz = (ORGN + (float)(cz + 1) * HCELL) - qz;
    float margin0 = fminf(fminf(fminf(mlx, mhx), fminf(mly, mhy)), fminf(mlz, mhz));

    int tot = 0, ovf = 0;

    // scan all cells intersecting ball(mfin); append keys < tkfin to sel.
    auto scan_ball = [&](int RB, float mfin, unsigned long long tkfin) {
        if (mfin <= 0.f) return;
        float mfin2 = mfin * mfin;
        int L = 2 * RB + 1, nrows = L * L;
        for (int r0 = 0; r0 < nrows; r0 += 64) {
            int nr = min(64, nrows - r0);
            int rr = r0 + lane;
            int num = 0, start = 0;
            if (rr < nrows) {
                int dzr = rr / L - RB, dyr = rr % L - RB;
                int zc = cz + dzr, yc = cy + dyr;
                if ((unsigned)zc < GD && (unsigned)yc < GD) {
                    float ylo = ORGN + (float)yc * HCELL;
                    float zlo = ORGN + (float)zc * HCELL;
                    float dyl = fmaxf(fmaxf(ylo - qy, qy - (ylo + HCELL)), 0.f);
                    float dzl = fmaxf(fmaxf(zlo - qz, qz - (zlo + HCELL)), 0.f);
                    float rem = mfin2 - dyl * dyl - dzl * dzl;
                    if (rem > -1e-4f) {
                        float xh = sqrtf(fmaxf(rem, 0.f)) + 1e-3f;  // cushion: include boundary cells
                        int xlo = max(0, (int)floorf((qx - xh - ORGN) * INVH));
                        int xhi = min(GD - 1, (int)floorf((qx + xh - ORGN) * INVH));
                        if (xlo <= xhi) {
                            int rowb = (zc * GD + yc) * GD;
                            start = rg[rowb + xlo].x;
                            num   = rg[rowb + xhi].y - start;
                        }
                    }
                }
            }
            int inc = wave_scan_incl(num, lane);
            int ctot = __shfl(inc, 63, 64);
            if (ctot == 0) continue;
            int excl = inc - num;
            // expand candidate index -> slot via 6-step shfl lower_bound, then gather
            auto eg = [&](int base, int& sv, float4& pv, bool& vld) {
                int t = base + lane;
                vld = t < ctot;
                int tc = vld ? t : (ctot - 1);
                int lo = 0, hi = nr - 1;
                #pragma unroll
                for (int st = 0; st < 6; ++st) {
                    int mid = (lo + hi + 1) >> 1;
                    int e = __shfl(excl, mid, 64);
                    bool g = (e <= tc);
                    lo = g ? mid : lo;
                    hi = g ? hi : (mid - 1);
                }
                sv = __shfl(start, lo, 64) + (tc - __shfl(excl, lo, 64));
                pv = spos[sv];
            };
            int s0; float4 p0; bool v0;
            eg(0, s0, p0, v0);
            for (int base = 0; base < ctot; base += 64) {
                int s1 = 0; float4 p1 = p0; bool v1 = false;
                if (base + 64 < ctot) eg(base + 64, s1, p1, v1);   // prefetch next chunk
                float d = pdist4(qx, qy, qz, qxx, p0.x, p0.y, p0.z);
                unsigned long long key = ((unsigned long long)fkey(d) << 27)
                                       | ((unsigned long long)(unsigned)__float_as_int(p0.w) << 14)
                                       | (unsigned)s0;
                bool pass = v0 && (key < tkfin);
                unsigned long long mk = __ballot(pass);
                int cnum = (int)__popcll(mk);
                if (tot + cnum > SEL_CAP) { ovf = 1; return; }
                if (pass) sel[tot + (int)__popcll(mk & ((1ULL << lane) - 1ULL))] = key;
                tot += cnum;
                s0 = s1; p0 = p1; v0 = v1;
            }
        }
    };

    auto count_below = [&](unsigned long long tk) {
        int c = 0;
        for (int t0 = 0; t0 < tot; t0 += 64) {
            int tt = t0 + lane;
            if (tt < tot) c += (sel[tt] < tk) ? 1 : 0;
        }
        for (int o = 32; o > 0; o >>= 1) c += __shfl_xor(c, o, 64);
        return c;
    };

    // ---- phase 1: ball(margin(RSTART)) ----
    float mfin1 = margin0 + (float)RSTART * HCELL;
    unsigned long long tkf1 = (mfin1 > 0.f) ? tkmake(mfin1) : 0ULL;
    if (tkf1) scan_ball(RSTART, mfin1, tkf1);

    unsigned long long tkey_sel = ~0ULL;
    int csel = 0;
    bool have = false;
    if (!ovf && tot >= 16) {
        float mA = margin0 + 1.0f * HCELL;
        if (mA > 0.f) {
            unsigned long long tkA = tkmake(mA);
            int cA = count_below(tkA);
            if (cA >= 16) { tkey_sel = tkA; csel = cA; have = true; }
        }
        if (!have) { tkey_sel = ~0ULL; csel = tot; have = true; }   // all of sel (< margin(RSTART))
    }
    if (!have && !ovf) {
        // ---- escalation: reset + rescan ball(margin(RESC)) ----
        tot = 0;
        float mfin4 = margin0 + (float)RESC * HCELL;
        unsigned long long tkf4 = (mfin4 > 0.f) ? tkmake(mfin4) : 0ULL;
        if (tkf4) scan_ball(RESC, mfin4, tkf4);
        if (!ovf && tot >= 16) {
            float mB = margin0 + (float)(RESC - 1) * HCELL;
            if (mB > 0.f) {
                unsigned long long tkB = tkmake(mB);
                int cB = count_below(tkB);
                if (cB >= 16) { tkey_sel = tkB; csel = cB; have = true; }
            }
            if (!have) { tkey_sel = ~0ULL; csel = tot; have = true; }
        }
    }

    if (!have) {
        // ---- two-pass ladder brute over all NPTS of this batch (R10-proven) ----
        const float LADR[16] = {0.35f, 0.4725f, 0.637875f, 0.86113125f,
                                1.1625272f, 1.5694117f, 2.1187058f, 2.8602529f,
                                3.8613414f, 5.2128109f, 7.0372947f, 9.5003478f,
                                12.825470f, 17.314384f, 23.374418f, 31.555464f};
        int sbase = b << 13;
        int cc[16];
        #pragma unroll
        for (int k = 0; k < 16; ++k) cc[k] = 0;
        for (int i0 = 0; i0 < NPTS; i0 += 64) {
            float4 p = spos[sbase + i0 + lane];
            float d = pdist4(qx, qy, qz, qxx, p.x, p.y, p.z);
            #pragma unroll
            for (int k = 0; k < 16; ++k) cc[k] += (d < LADR[k] * LADR[k]) ? 1 : 0;
        }
        #pragma unroll
        for (int k = 0; k < 16; ++k)
            for (int o = 32; o > 0; o >>= 1) cc[k] += __shfl_xor(cc[k], o, 64);
        float Tq = LADR[15] * LADR[15]; int cL = cc[15];
        #pragma unroll
        for (int k = 14; k >= 0; --k) if (cc[k] >= 16) { Tq = LADR[k] * LADR[k]; cL = cc[k]; }
        if (cL <= SEL_CAP) {
            tot = 0;
            for (int i0 = 0; i0 < NPTS; i0 += 64) {
                int idx = sbase + i0 + lane;
                float4 p = spos[idx];
                float d = pdist4(qx, qy, qz, qxx, p.x, p.y, p.z);
                bool pass = (d < Tq);
                unsigned long long key = ((unsigned long long)fkey(d) << 27)
                                       | ((unsigned long long)(unsigned)__float_as_int(p.w) << 14)
                                       | (unsigned)idx;
                unsigned long long mk = __ballot(pass);
                if (pass) sel[tot + (int)__popcll(mk & ((1ULL << lane) - 1ULL))] = key;
                tot += (int)__popcll(mk);
            }
            tkey_sel = ~0ULL;
            csel = tot;
        } else {
            // ultra-rare capacity fallback: per-lane top16 in sel region + 16-round extract
            unsigned long long* mybuf = sel + lane;   // element j at [j*64]
            unsigned long long minkey = ~0ULL, maxkey = 0;
            int nbuf = 0;
            for (int i = lane; i < NPTS; i += 64) {
                float4 p = spos[sbase + i];
                float d = pdist4(qx, qy, qz, qxx, p.x, p.y, p.z);
                unsigned long long key = ((unsigned long long)fkey(d) << 27)
                                       | ((unsigned long long)(unsigned)__float_as_int(p.w) << 14)
                                       | (unsigned)(sbase + i);
                if (nbuf < 16) {
                    mybuf[(size_t)nbuf * 64] = key;
                    ++nbuf;
                    minkey = (key < minkey) ? key : minkey;
                    maxkey = (key > maxkey) ? key : maxkey;
                } else if (key < maxkey) {
                    unsigned long long vmax = 0, v2 = 0;
                    int pmax = 0;
                    #pragma unroll
                    for (int j = 0; j < 16; ++j) {
                        unsigned long long v = mybuf[(size_t)j * 64];
                        if (v > vmax) { v2 = vmax; vmax = v; pmax = j; }
                        else if (v > v2) { v2 = v; }
                    }
                    mybuf[(size_t)pmax * 64] = key;
                    maxkey = (key > v2) ? key : v2;
                    minkey = (key < minkey) ? key : minkey;
                }
            }
            unsigned long long keep = ~0ULL;
            for (int k = 0; k < 16; ++k) {
                unsigned long long m = minkey;
                for (int o = 32; o > 0; o >>= 1) {
                    unsigned long long pv = shflx64(m, o);
                    m = (pv < m) ? pv : m;
                }
                unsigned long long bal = __ballot(minkey == m);
                int wl = __ffsll((long long)bal) - 1;
                if (lane == wl) {
                    int pos = 0;
                    for (int j = 0; j < nbuf; ++j) if (mybuf[(size_t)j * 64] == m) pos = j;
                    --nbuf;
                    mybuf[(size_t)pos * 64] = mybuf[(size_t)nbuf * 64];
                    unsigned long long nm = ~0ULL;
                    for (int j = 0; j < nbuf; ++j) {
                        unsigned long long v = mybuf[(size_t)j * 64];
                        nm = (v < nm) ? v : nm;
                    }
                    minkey = nm;
                }
                if (lane == k) keep = m;
            }
            float rx = 0.f, ry = 0.f, rz = 0.f, rd = 0.f;
            if (lane < 16) {
                int sp = (int)(keep & 0x3FFFu);
                int oi = (int)((keep >> 14) & 0x1FFFu);
                float4 p = spos[sp];
                rx = p.x - qx; ry = p.y - qy; rz = p.z - qz;
                rd = sqrtf(__fadd_rn(__fadd_rn(__fmul_rn(rx, rx), __fmul_rn(ry, ry)), __fmul_rn(rz, rz)));
                knn[(((size_t)b << 13) + nq) * 16 + lane] = oi;
            }
            for (int o = 8; o > 0; o >>= 1) {
                rx += __shfl_xor(rx, o, 64);
                ry += __shfl_xor(ry, o, 64);
                rz += __shfl_xor(rz, o, 64);
                rd += __shfl_xor(rd, o, 64);
            }
            if (lane == 0) {
                const float inv16 = 0.0625f;
                spatial[((size_t)b * 4 + 0) * NPTS + nq] = rx * inv16;
                spatial[((size_t)b * 4 + 1) * NPTS + nq] = ry * inv16;
                spatial[((size_t)b * 4 + 2) * NPTS + nq] = rz * inv16;
                spatial[((size_t)b * 4 + 3) * NPTS + nq] = rd * inv16;
            }
            return;
        }
    }

    // -------- shared selection: compact keys < tkey_sel, then rank-count --------
    const unsigned long long* src = sel;
    int m = tot;
    if (tkey_sel != ~0ULL && csel <= 512) {
        int w = 0;
        for (int t0 = 0; t0 < tot; t0 += 64) {
            int tt = t0 + lane;
            unsigned long long v = (tt < tot) ? sel[tt] : ~0ULL;
            bool pass = (tt < tot) && (v < tkey_sel);
            unsigned long long mk = __ballot(pass);
            if (pass) sel2[w + (int)__popcll(mk & ((1ULL << lane) - 1ULL))] = v;
            w += (int)__popcll(mk);
        }
        asm volatile("s_waitcnt lgkmcnt(0)" ::: "memory");
        __builtin_amdgcn_sched_barrier(0);
        src = sel2; m = w;
        tkey_sel = ~0ULL;   // compacted list is fully qualified
    }
    float rxs = 0.f, rys = 0.f, rzs = 0.f, rds = 0.f;
    for (int t0 = 0; t0 < m; t0 += 64) {
        int tt = t0 + lane;
        if (tt < m) {
            unsigned long long kt = src[tt];
            if (kt < tkey_sel) {
                int rr = 0;
                for (int j = 0; j < m; ++j) rr += (src[j] < kt) ? 1 : 0;   // broadcast reads
                if (rr < 16) {
                    int sp = (int)(kt & 0x3FFFu);
                    int oi = (int)((kt >> 14) & 0x1FFFu);
                    float4 p = spos[sp];
                    float dx = p.x - qx, dy = p.y - qy, dz = p.z - qz;
                    float dl = sqrtf(__fadd_rn(__fadd_rn(__fmul_rn(dx, dx), __fmul_rn(dy, dy)), __fmul_rn(dz, dz)));
                    knn[(((size_t)b << 13) + nq) * 16 + rr] = oi;
                    rxs += dx; rys += dy; rzs += dz; rds += dl;
                }
            }
        }
    }
    for (int o = 32; o > 0; o >>= 1) {
        rxs += __shfl_xor(rxs, o, 64);
        rys += __shfl_xor(rys, o, 64);
        rzs += __shfl_xor(rzs, o, 64);
        rds += __shfl_xor(rds, o, 64);
    }
    if (lane == 0) {
        const float inv16 = 0.0625f;
        spatial[((size_t)b * 4 + 0) * NPTS + nq] = rxs * inv16;
        spatial[((size_t)b * 4 + 1) * NPTS + nq] = rys * inv16;
        spatial[((size_t)b * 4 + 2) * NPTS + nq] = rzs * inv16;
        spatial[((size_t)b * 4 + 3) * NPTS + nq] = rds * inv16;
    }
}

// ---------------- x[B,C,N] -> xT[B,N,C] ----------------
__global__ void transpose_k(const float* __restrict__ x, float* __restrict__ xT) {
    __shared__ float tl[32][33];
    int b = blockIdx.z;
    int n0 = blockIdx.x * 32, c0 = blockIdx.y * 32;
    int tx = threadIdx.x, ty = threadIdx.y;
    const float* xb = x + (size_t)b * 128 * NN;
    float* xtb = xT + (size_t)b * NN * 128;
    for (int i = 0; i < 32; i += 8) tl[ty + i][tx] = xb[(size_t)(c0 + ty + i) * NN + n0 + tx];
    __syncthreads();
    for (int i = 0; i < 32; i += 8) xtb[(size_t)(n0 + ty + i) * 128 + c0 + tx] = tl[tx][ty + i];
}

// ---------------- max_k(x[:,idx_k]) - x  -> md[B,128,N] ----------------
__global__ __launch_bounds__(256) void md_k(const float* __restrict__ xT,
                                            const int* __restrict__ knn,
                                            float* __restrict__ md) {
    __shared__ int ki[8][16];
    __shared__ float smd[8][132];
    int b = blockIdx.y;
    int n0 = blockIdx.x * 8;
    int tid = threadIdx.x;
    if (tid < 128) ki[tid >> 4][tid & 15] = knn[(((size_t)b << 13) + n0 + (tid >> 4)) * 16 + (tid & 15)];
    __syncthreads();
    int nl = tid >> 5;
    int c4 = (tid & 31) * 4;
    const float* xb = xT + (size_t)b * NPTS * 128;
    float4 m = make_float4(-3.0e38f, -3.0e38f, -3.0e38f, -3.0e38f);
    #pragma unroll
    for (int k = 0; k < 16; ++k) {
        const float4 g = *(const float4*)(xb + (size_t)ki[nl][k] * 128 + c4);
        m.x = fmaxf(m.x, g.x); m.y = fmaxf(m.y, g.y); m.z = fmaxf(m.z, g.z); m.w = fmaxf(m.w, g.w);
    }
    const float4 own = *(const float4*)(xb + (size_t)(n0 + nl) * 128 + c4);
    m.x -= own.x; m.y -= own.y; m.z -= own.z; m.w -= own.w;
    *(float4*)(&smd[nl][c4]) = m;
    __syncthreads();
    for (int r = 0; r < 4; ++r) {
        int c = (tid >> 3) + 32 * r;
        int n2 = tid & 7;
        md[((size_t)b * 128 + c) * NN + n0 + n2] = smd[n2][c];
    }
}

// ---------------- fold conv-bias + BN into per-channel scale/shift ----------------
__global__ void prep_k(const float* bb1, const float* g1, const float* be1, const float* m1, const float* v1,
                       const float* bb2, const float* g2, const float* be2, const float* m2, const float* v2,
                       const float* sb1, const float* gs,  const float* bes, const float* ms, const float* vs,
                       const float* sb2,
                       const float* ab1, const float* ga,  const float* bea, const float* ma, const float* va,
                       const float* ab2, float* sc) {
    int t = threadIdx.x;
    if (t < 128) {
        float i1 = g1[t] / sqrtf(v1[t] + 1e-5f);
        sc[t] = i1;        sc[128 + t] = bb1[t] * i1 + be1[t] - m1[t] * i1;
        float i2 = g2[t] / sqrtf(v2[t] + 1e-5f);
        sc[256 + t] = i2;  sc[384 + t] = bb2[t] * i2 + be2[t] - m2[t] * i2;
        sc[832 + t] = 1.0f; sc[960 + t] = ab2[t];
    }
    if (t < 32) {
        float is = gs[t] / sqrtf(vs[t] + 1e-5f);
        sc[512 + t] = is;  sc[544 + t] = sb1[t] * is + bes[t] - ms[t] * is;
    }
    if (t < 64) {
        sc[576 + t] = 1.0f; sc[640 + t] = sb2[t];
        float ia = ga[t] / sqrtf(va[t] + 1e-5f);
        sc[704 + t] = ia;  sc[768 + t] = ab1[t] * ia + bea[t] - ma[t] * ia;
    }
}

// ---------------- generic 1x1-conv (+folded BN, activation) — spatial MLP only ----------------
template <int O, int K, int TILE_N, int SPLIT, int ACT>
__global__ __launch_bounds__(256) void conv_bn(const float* __restrict__ srcA,
                                               const float* __restrict__ srcB,
                                               const float* __restrict__ W,
                                               const float* __restrict__ scale,
                                               const float* __restrict__ shift,
                                               float* __restrict__ out) {
    constexpr int KC  = (K < 64) ? K : 64;
    constexpr int NT4 = TILE_N / 4;
    constexpr int O4  = O / 4;
    static_assert(NT4 * O4 == 256, "thread mapping");
    __shared__ float wT[KC][O + 4];
    __shared__ float inT[KC][TILE_N];
    int tid = threadIdx.x;
    int b = blockIdx.z;
    int n0 = blockIdx.x * TILE_N;
    int n_thr = tid % NT4;
    int o_thr = tid / NT4;
    float acc[4][4] = {{0.f, 0.f, 0.f, 0.f}, {0.f, 0.f, 0.f, 0.f}, {0.f, 0.f, 0.f, 0.f}, {0.f, 0.f, 0.f, 0.f}};

    for (int k0 = 0; k0 < K; k0 += KC) {
        for (int idx = tid; idx < KC * O; idx += 256) {
            int cc = idx % KC;
            int o  = idx / KC;
            wT[cc][o] = W[(size_t)o * K + k0 + cc];
        }
        for (int idx = tid; idx < KC * NT4; idx += 256) {
            int cc = idx / NT4;
            int nf = idx % NT4;
            int cg = k0 + cc;
            const float* src = (cg < SPLIT)
                ? (srcA + ((size_t)b * SPLIT + cg) * NN)
                : (srcB + ((size_t)b * (K - SPLIT) + (cg - SPLIT)) * NN);
            *(float4*)(&inT[cc][nf * 4]) = *(const float4*)(src + n0 + nf * 4);
        }
        __syncthreads();
        #pragma unroll 8
        for (int c = 0; c < KC; ++c) {
            float4 wv = *(const float4*)(&wT[c][o_thr * 4]);
            float4 iv = *(const float4*)(&inT[c][n_thr * 4]);
            acc[0][0] = fmaf(wv.x, iv.x, acc[0][0]); acc[0][1] = fmaf(wv.x, iv.y, acc[0][1]);
            acc[0][2] = fmaf(wv.x, iv.z, acc[0][2]); acc[0][3] = fmaf(wv.x, iv.w, acc[0][3]);
            acc[1][0] = fmaf(wv.y, iv.x, acc[1][0]); acc[1][1] = fmaf(wv.y, iv.y, acc[1][1]);
            acc[1][2] = fmaf(wv.y, iv.z, acc[1][2]); acc[1][3] = fmaf(wv.y, iv.w, acc[1][3]);
            acc[2][0] = fmaf(wv.z, iv.x, acc[2][0]); acc[2][1] = fmaf(wv.z, iv.y, acc[2][1]);
            acc[2][2] = fmaf(wv.z, iv.z, acc[2][2]); acc[2][3] = fmaf(wv.z, iv.w, acc[2][3]);
            acc[3][0] = fmaf(wv.w, iv.x, acc[3][0]); acc[3][1] = fmaf(wv.w, iv.y, acc[3][1]);
            acc[3][2] = fmaf(wv.w, iv.z, acc[3][2]); acc[3][3] = fmaf(wv.w, iv.w, acc[3][3]);
        }
        __syncthreads();
    }
    #pragma unroll
    for (int j = 0; j < 4; ++j) {
        int o = o_thr * 4 + j;
        float scv = scale[o], shv = shift[o];
        float4 v;
        v.x = fmaf(acc[j][0], scv, shv);
        v.y = fmaf(acc[j][1], scv, shv);
        v.z = fmaf(acc[j][2], scv, shv);
        v.w = fmaf(acc[j][3], scv, shv);
        size_t obase = ((size_t)b * O + o) * NN + n0 + n_thr * 4;
        if (ACT == 1) {
            v.x = fmaxf(v.x, 0.f); v.y = fmaxf(v.y, 0.f); v.z = fmaxf(v.z, 0.f); v.w = fmaxf(v.w, 0.f);
        }
        *(float4*)(out + obase) = v;
    }
}

#define FMA16(ACCV, WV, IV) \
    ACCV[0][0] = fmaf(WV.x, IV.x, ACCV[0][0]); ACCV[0][1] = fmaf(WV.x, IV.y, ACCV[0][1]); \
    ACCV[0][2] = fmaf(WV.x, IV.z, ACCV[0][2]); ACCV[0][3] = fmaf(WV.x, IV.w, ACCV[0][3]); \
    ACCV[1][0] = fmaf(WV.y, IV.x, ACCV[1][0]); ACCV[1][1] = fmaf(WV.y, IV.y, ACCV[1][1]); \
    ACCV[1][2] = fmaf(WV.y, IV.z, ACCV[1][2]); ACCV[1][3] = fmaf(WV.y, IV.w, ACCV[1][3]); \
    ACCV[2][0] = fmaf(WV.z, IV.x, ACCV[2][0]); ACCV[2][1] = fmaf(WV.z, IV.y, ACCV[2][1]); \
    ACCV[2][2] = fmaf(WV.z, IV.z, ACCV[2][2]); ACCV[2][3] = fmaf(WV.z, IV.w, ACCV[2][3]); \
    ACCV[3][0] = fmaf(WV.w, IV.x, ACCV[3][0]); ACCV[3][1] = fmaf(WV.w, IV.y, ACCV[3][1]); \
    ACCV[3][2] = fmaf(WV.w, IV.z, ACCV[3][2]); ACCV[3][3] = fmaf(WV.w, IV.w, ACCV[3][3])

// ---------------- fused boundary net: [x;md] 256->128 (bn,relu) -> 128->128 (bn,relu) ----------------
// Stage-1 output tile kept in LDS (y1t) — removes the y1b HBM round-trip + a dispatch.
// Per-output arithmetic identical to the unfused conv_bn (same fmaf order, same scale/shift).
__global__ __launch_bounds__(256) void fused_boundary(const float* __restrict__ x,
                                                      const float* __restrict__ md,
                                                      const float* __restrict__ W1,
                                                      const float* __restrict__ W2,
                                                      const float* __restrict__ sc,
                                                      float* __restrict__ y2b) {
    __shared__ float wT[64][132];    // 33.8 KB
    __shared__ float inT[64][32];    // 8 KB
    __shared__ float y1t[128][32];   // 16 KB
    int tid = threadIdx.x;
    int b = blockIdx.z;
    int n0 = blockIdx.x * 32;
    int n_thr = tid % 8;
    int o_thr = tid / 8;             // 0..31
    float acc[4][4] = {{0.f,0.f,0.f,0.f},{0.f,0.f,0.f,0.f},{0.f,0.f,0.f,0.f},{0.f,0.f,0.f,0.f}};

    // stage 1: [x;md] 256 -> 128, bn+relu -> y1t
    for (int k0 = 0; k0 < 256; k0 += 64) {
        for (int idx = tid; idx < 64 * 128; idx += 256) {
            int cc = idx % 64;
            int o  = idx / 64;
            wT[cc][o] = W1[(size_t)o * 256 + k0 + cc];
        }
        for (int idx = tid; idx < 64 * 8; idx += 256) {
            int cc = idx / 8;
            int nf = idx % 8;
            int cg = k0 + cc;
            const float* src = (cg < 128)
                ? (x  + ((size_t)b * 128 + cg) * NN)
                : (md + ((size_t)b * 128 + (cg - 128)) * NN);
            *(float4*)(&inT[cc][nf * 4]) = *(const float4*)(src + n0 + nf * 4);
        }
        __syncthreads();
        #pragma unroll 8
        for (int c = 0; c < 64; ++c) {
            float4 wv = *(const float4*)(&wT[c][o_thr * 4]);
            float4 iv = *(const float4*)(&inT[c][n_thr * 4]);
            FMA16(acc, wv, iv);
        }
        __syncthreads();
    }
    #pragma unroll
    for (int j = 0; j < 4; ++j) {
        int o = o_thr * 4 + j;
        float scv = sc[o], shv = sc[128 + o];
        float4 v;
        v.x = fmaxf(fmaf(acc[j][0], scv, shv), 0.f);
        v.y = fmaxf(fmaf(acc[j][1], scv, shv), 0.f);
        v.z = fmaxf(fmaf(acc[j][2], scv, shv), 0.f);
        v.w = fmaxf(fmaf(acc[j][3], scv, shv), 0.f);
        *(float4*)(&y1t[o][n_thr * 4]) = v;
    }
    __syncthreads();

    // stage 2: 128 -> 128, bn+relu -> y2b (reads y1t from LDS)
    float a2[4][4] = {{0.f,0.f,0.f,0.f},{0.f,0.f,0.f,0.f},{0.f,0.f,0.f,0.f},{0.f,0.f,0.f,0.f}};
    for (int k0 = 0; k0 < 128; k0 += 64) {
        for (int idx = tid; idx < 64 * 128; idx += 256) {
            int cc = idx % 64;
            int o  = idx / 64;
            wT[cc][o] = W2[(size_t)o * 128 + k0 + cc];
        }
        __syncthreads();
        #pragma unroll 8
        for (int c = 0; c < 64; ++c) {
            float4 wv = *(const float4*)(&wT[c][o_thr * 4]);
            float4 iv = *(const float4*)(&y1t[k0 + c][n_thr * 4]);
            FMA16(a2, wv, iv);
        }
        __syncthreads();
    }
    #pragma unroll
    for (int j = 0; j < 4; ++j) {
        int o = o_thr * 4 + j;
        float scv = sc[256 + o], shv = sc[384 + o];
        float4 v;
        v.x = fmaxf(fmaf(a2[j][0], scv, shv), 0.f);
        v.y = fmaxf(fmaf(a2[j][1], scv, shv), 0.f);
        v.z = fmaxf(fmaf(a2[j][2], scv, shv), 0.f);
        v.w = fmaxf(fmaf(a2[j][3], scv, shv), 0.f);
        *(float4*)(y2b + ((size_t)b * 128 + o) * NN + n0 + n_thr * 4) = v;
    }
}

// ---------------- fused attention: [x;sfeat] 192->64 (bn,relu) -> 64->128 sigmoid + final fuse ----------------
__global__ __launch_bounds__(256) void fused_attn(const float* __restrict__ x,
                                                  const float* __restrict__ sfb,
                                                  const float* __restrict__ W1,
                                                  const float* __restrict__ W2,
                                                  const float* __restrict__ sc,
                                                  const float* __restrict__ y2b,
                                                  float* __restrict__ dout) {
    __shared__ float wT[64][68];     // 17.4 KB
    __shared__ float inT[64][64];    // 16 KB
    __shared__ float a1t[64][64];    // 16 KB
    int tid = threadIdx.x;
    int b = blockIdx.z;
    int n0 = blockIdx.x * 64;
    int n_thr = tid % 16;
    int o_thr = tid / 16;            // 0..15
    float acc[4][4] = {{0.f,0.f,0.f,0.f},{0.f,0.f,0.f,0.f},{0.f,0.f,0.f,0.f},{0.f,0.f,0.f,0.f}};

    // stage 1: [x;sfb] 192 -> 64, bn+relu -> a1t
    for (int k0 = 0; k0 < 192; k0 += 64) {
        for (int idx = tid; idx < 64 * 64; idx += 256) {
            int cc = idx % 64;
            int o  = idx / 64;
            wT[cc][o] = W1[(size_t)o * 192 + k0 + cc];
        }
        for (int idx = tid; idx < 64 * 16; idx += 256) {
            int cc = idx / 16;
            int nf = idx % 16;
            int cg = k0 + cc;
            const float* src = (cg < 128)
                ? (x   + ((size_t)b * 128 + cg) * NN)
                : (sfb + ((size_t)b * 64 + (cg - 128)) * NN);
            *(float4*)(&inT[cc][nf * 4]) = *(const float4*)(src + n0 + nf * 4);
        }
        __syncthreads();
        #pragma unroll 8
        for (int c = 0; c < 64; ++c) {
            float4 wv = *(const float4*)(&wT[c][o_thr * 4]);
            float4 iv = *(const float4*)(&inT[c][n_thr * 4]);
            FMA16(acc, wv, iv);
        }
        __syncthreads();
    }
    #pragma unroll
    for (int j = 0; j < 4; ++j) {
        int o = o_thr * 4 + j;
        float scv = sc[704 + o], shv = sc[768 + o];
        float4 v;
        v.x = fmaxf(fmaf(acc[j][0], scv, shv), 0.f);
        v.y = fmaxf(fmaf(acc[j][1], scv, shv), 0.f);
        v.z = fmaxf(fmaf(acc[j][2], scv, shv), 0.f);
        v.w = fmaxf(fmaf(acc[j][3], scv, shv), 0.f);
        *(float4*)(&a1t[o][n_thr * 4]) = v;
    }
    __syncthreads();

    // stage 2: 64 -> 128 in two o-halves; sigmoid + dout = x + y2*attn
    for (int oh = 0; oh < 128; oh += 64) {
        for (int idx = tid; idx < 64 * 64; idx += 256) {
            int cc = idx % 64;
            int o  = idx / 64;
            wT[cc][o] = W2[(size_t)(oh + o) * 64 + cc];
        }
        __syncthreads();
        float a2[4][4] = {{0.f,0.f,0.f,0.f},{0.f,0.f,0.f,0.f},{0.f,0.f,0.f,0.f},{0.f,0.f,0.f,0.f}};
        #pragma unroll 8
        for (int c = 0; c < 64; ++c) {
            float4 wv = *(const float4*)(&wT[c][o_thr * 4]);
            float4 iv = *(const float4*)(&a1t[c][n_thr * 4]);
            FMA16(a2, wv, iv);
        }
        #pragma unroll
        for (int j = 0; j < 4; ++j) {
            int o = oh + o_thr * 4 + j;
            float scv = sc[832 + o], shv = sc[960 + o];
            float4 v;
            v.x = fmaf(a2[j][0], scv, shv);
            v.y = fmaf(a2[j][1], scv, shv);
            v.z = fmaf(a2[j][2], scv, shv);
            v.w = fmaf(a2[j][3], scv, shv);
            size_t obase = ((size_t)b * 128 + o) * NN + n0 + n_thr * 4;
            float4 xr = *(const float4*)(x + obase);
            float4 yr = *(const float4*)(y2b + obase);
            v.x = xr.x + yr.x / (1.f + __expf(-v.x));
            v.y = xr.y + yr.y / (1.f + __expf(-v.y));
            v.z = xr.z + yr.z / (1.f + __expf(-v.z));
            v.w = xr.w + yr.w / (1.f + __expf(-v.w));
            *(float4*)(dout + obase) = v;
        }
        __syncthreads();   // wT reads done before next half reloads
    }
}

extern "C" void kernel_launch(void* const* d_in, const int* in_sizes, int n_in,
                              void* d_out, int out_size, void* d_ws, size_t ws_size,
                              hipStream_t stream) {
    (void)in_sizes; (void)n_in; (void)out_size; (void)ws_size;
    const float* x    = (const float*)d_in[0];
    const float* xyz  = (const float*)d_in[1];
    const float* bw1  = (const float*)d_in[2];
    const float* bb1  = (const float*)d_in[3];
    const float* bn1g = (const float*)d_in[4];
    const float* bn1b = (const float*)d_in[5];
    const float* bn1m = (const float*)d_in[6];
    const float* bn1v = (const float*)d_in[7];
    const float* bw2  = (const float*)d_in[8];
    const float* bb2  = (const float*)d_in[9];
    const float* bn2g = (const float*)d_in[10];
    const float* bn2b = (const float*)d_in[11];
    const float* bn2m = (const float*)d_in[12];
    const float* bn2v = (const float*)d_in[13];
    const float* sw1  = (const float*)d_in[14];
    const float* sb1  = (const float*)d_in[15];
    const float* sbng = (const float*)d_in[16];
    const float* sbnb = (const float*)d_in[17];
    const float* sbnm = (const float*)d_in[18];
    const float* sbnv = (const float*)d_in[19];
    const float* sw2  = (const float*)d_in[20];
    const float* sb2  = (const float*)d_in[21];
    const float* aw1  = (const float*)d_in[22];
    const float* ab1  = (const float*)d_in[23];
    const float* abng = (const float*)d_in[24];
    const float* abnb = (const float*)d_in[25];
    const float* abnm = (const float*)d_in[26];
    const float* abnv = (const float*)d_in[27];
    const float* aw2  = (const float*)d_in[28];
    const float* ab2  = (const float*)d_in[29];

    char* ws = (char*)d_ws;
    int*    cnt    = (int*)(ws + OFF_CNT);
    int*    offs   = (int*)(ws + OFF_OFFS);
    int*    cellid = (int*)(ws + OFF_CELLID);
    int*    rank   = (int*)(ws + OFF_RANK);
    float4* spos   = (float4*)(ws + OFF_SPOS);
    int*    knn    = (int*)(ws + OFF_KNN);
    float*  spat   = (float*)(ws + OFF_SPATIAL);
    float*  xT     = (float*)(ws + OFF_XT);
    float*  md     = (float*)(ws + OFF_MD);
    float*  s1b    = (float*)(ws + OFF_S1);
    float*  sfb    = (float*)(ws + OFF_SF);
    float*  y2b    = (float*)(ws + OFF_Y2);
    float*  sc     = (float*)(ws + OFF_SC);
    int*    bsum   = (int*)(ws + OFF_BSUM);
    int*    bpre   = (int*)(ws + OFF_BPRE);
    int2*   rng    = (int2*)(ws + OFF_RNG);
    float*  dout   = (float*)d_out;

    hipMemsetAsync(cnt, 0, (size_t)TOTC * 4, stream);
    cell_build<<<dim3((NTOT + 255) / 256), 256, 0, stream>>>(xyz, cnt, cellid, rank);
    scan_sums<<<dim3(NBLK_SCAN), 256, 0, stream>>>(cnt, bsum);
    scan_top<<<dim3(1), 512, 0, stream>>>(bsum, bpre);
    scan_write<<<dim3(NBLK_SCAN), 256, 0, stream>>>(cnt, bpre, offs, rng);
    scatter_k<<<dim3((NTOT + 255) / 256), 256, 0, stream>>>(xyz, cellid, rank, offs, spos);
    knn_kernel<<<dim3(NTOT), 64, 0, stream>>>(spos, rng, knn, spat);
    transpose_k<<<dim3(NPTS / 32, 128 / 32, NB), dim3(32, 8), 0, stream>>>(x, xT);
    md_k<<<dim3(NPTS / 8, NB), 256, 0, stream>>>(xT, knn, md);
    prep_k<<<1, 128, 0, stream>>>(bb1, bn1g, bn1b, bn1m, bn1v,
                                  bb2, bn2g, bn2b, bn2m, bn2v,
                                  sb1, sbng, sbnb, sbnm, sbnv,
                                  sb2,
                                  ab1, abng, abnb, abnm, abnv,
                                  ab2, sc);
    // spatial MLP: 4->32 (bn,relu), 32->64
    conv_bn<32, 4, 128, 4, 1><<<dim3(NPTS / 128, 1, NB), 256, 0, stream>>>(
        spat, spat, sw1, sc + 512, sc + 544, s1b);
    conv_bn<64, 32, 64, 32, 0><<<dim3(NPTS / 64, 1, NB), 256, 0, stream>>>(
        s1b, s1b, sw2, sc + 576, sc + 640, sfb);
    // fused boundary net: [x;md] 256->128 (bn,relu) -> 128->128 (bn,relu)
    fused_boundary<<<dim3(NPTS / 32, 1, NB), 256, 0, stream>>>(x, md, bw1, bw2, sc, y2b);
    // fused attention: [x;sfeat] 192->64 (bn,relu) -> 64->128 sigmoid + final fuse
    fused_attn<<<dim3(NPTS / 64, 1, NB), 256, 0, stream>>>(x, sfb, aw1, aw2, sc, y2b, dout);
}

// Round 10
// 319.013 us; speedup vs baseline: 4.3790x; 1.0081x over previous
//
#include <hip/hip_runtime.h>
#include <math.h>

#define NPTS  8192
#define NB    2
#define NTOT  (NPTS*NB)
#define GD    60
#define NCELL (GD*GD*GD)
#define TOTC  (NB*NCELL)
#define HCELL 0.2f
#define INVH  5.0f
#define ORGN  (-6.0f)
#define NN    8192
#define SCAN_CHUNK 1024
#define NBLK_SCAN  ((TOTC + SCAN_CHUNK - 1) / SCAN_CHUNK)
#define RSTART    2    // phase-1 ball radius = margin(RSTART)
#define RESC      4    // escalation ball radius = margin(RESC)
#define SEL_CAP  1024  // appended-key list (u64, 8KB)

// ---------------- workspace layout (bytes) ----------------
#define OFF_CNT     ((size_t)0)
#define OFF_OFFS    (OFF_CNT    + (size_t)TOTC*4)
#define OFF_CELLID  (OFF_OFFS   + (size_t)TOTC*4)
#define OFF_RANK    (OFF_CELLID + (size_t)NTOT*4)
#define OFF_SPOS    (OFF_RANK   + (size_t)NTOT*4)          // float4 * NTOT (w = origidx bits)
#define OFF_KNN     (OFF_SPOS   + (size_t)NTOT*16)         // int * NTOT*16
#define OFF_SPATIAL (OFF_KNN    + (size_t)NTOT*16*4)       // [B,4,N]
#define OFF_XT      (OFF_SPATIAL+ (size_t)NB*4*NPTS*4)     // [B,N,128]
#define OFF_MD      (OFF_XT     + (size_t)NB*128*NPTS*4)   // [B,128,N]
#define OFF_S1      (OFF_MD     + (size_t)NB*128*NPTS*4)   // [B,32,N]
#define OFF_SF      (OFF_S1     + (size_t)NB*32*NPTS*4)    // [B,64,N]
#define OFF_Y1      (OFF_SF     + (size_t)NB*64*NPTS*4)    // [B,128,N] (unused after fusion)
#define OFF_Y2      (OFF_Y1     + (size_t)NB*128*NPTS*4)   // [B,128,N]
#define OFF_A1      (OFF_Y2     + (size_t)NB*128*NPTS*4)   // [B,64,N]  (unused after fusion)
#define OFF_SC      (OFF_A1     + (size_t)NB*64*NPTS*4)    // 1088 floats
#define OFF_BSUM    (OFF_SC     + (size_t)1088*4)          // NBLK_SCAN ints
#define OFF_BPRE    (OFF_BSUM   + (size_t)NBLK_SCAN*4)     // NBLK_SCAN ints
#define OFF_RNG     (((OFF_BPRE + (size_t)NBLK_SCAN*4) + 15) & ~(size_t)15)  // int2 * TOTC

// Replicate reference arithmetic exactly (no fma contraction).
static __device__ __forceinline__ float sumsq3(float x, float y, float z) {
    return __fadd_rn(__fadd_rn(__fmul_rn(x, x), __fmul_rn(y, y)), __fmul_rn(z, z));
}
static __device__ __forceinline__ float pdist4(float qx, float qy, float qz, float qxx,
                                               float px, float py, float pz) {
    float pxx = sumsq3(px, py, pz);
    float dot = __fadd_rn(__fadd_rn(__fmul_rn(qx, px), __fmul_rn(qy, py)), __fmul_rn(qz, pz));
    return __fsub_rn(__fadd_rn(qxx, pxx), __fadd_rn(dot, dot));
}
// monotone unsigned key for float (handles tiny negative self-distance)
static __device__ __forceinline__ unsigned fkey(float f) {
    unsigned b = __float_as_uint(f);
    return b ^ ((unsigned)(((int)b) >> 31) | 0x80000000u);
}
static __device__ __forceinline__ unsigned long long shflx64(unsigned long long v, int m) {
    unsigned lo = __shfl_xor((unsigned)v, m, 64);
    unsigned hi = __shfl_xor((unsigned)(v >> 32), m, 64);
    return ((unsigned long long)hi << 32) | lo;
}
// inclusive wave prefix-sum (all 64 lanes active)
static __device__ __forceinline__ int wave_scan_incl(int v, int lane) {
    #pragma unroll
    for (int d = 1; d < 64; d <<= 1) {
        int u = __shfl_up(v, d, 64);
        v += (lane >= d) ? u : 0;
    }
    return v;
}
// key threshold from margin m (>0): all keys strictly below are certified-complete
static __device__ __forceinline__ unsigned long long tkmake(float m) {
    return ((unsigned long long)(fkey(__fsub_rn(__fmul_rn(m, m), 1e-4f)) + 1u)) << 27;
}

// ---------------- grid build ----------------
__global__ void cell_build(const float* __restrict__ xyz, int* __restrict__ cnt,
                           int* __restrict__ cellid, int* __restrict__ rank) {
    int t = blockIdx.x * 256 + threadIdx.x;
    if (t >= NTOT) return;
    const float* p = xyz + (size_t)t * 3;
    float x = p[0], y = p[1], z = p[2];
    int cx = min(GD - 1, max(0, (int)floorf((x - ORGN) * INVH)));
    int cy = min(GD - 1, max(0, (int)floorf((y - ORGN) * INVH)));
    int cz = min(GD - 1, max(0, (int)floorf((z - ORGN) * INVH)));
    int gcell = (t >> 13) * NCELL + (cz * GD + cy) * GD + cx;
    rank[t] = atomicAdd(&cnt[gcell], 1);
    cellid[t] = gcell;
}

// -------- hierarchical exclusive scan of cnt[TOTC] -> offs[TOTC] (+rng int2) --------
__global__ __launch_bounds__(256) void scan_sums(const int* __restrict__ cnt, int* __restrict__ bsum) {
    __shared__ int red[256];
    int blk = blockIdx.x, t = threadIdx.x;
    int i0 = blk * SCAN_CHUNK + t * 4;
    int s = 0;
    if (i0 + 3 < TOTC) {
        int4 v = *(const int4*)(cnt + i0);
        s = v.x + v.y + v.z + v.w;
    } else {
        for (int j = 0; j < 4; ++j) if (i0 + j < TOTC) s += cnt[i0 + j];
    }
    red[t] = s;
    __syncthreads();
    for (int d = 128; d > 0; d >>= 1) {
        if (t < d) red[t] += red[t + d];
        __syncthreads();
    }
    if (t == 0) bsum[blk] = red[0];
}

__global__ __launch_bounds__(512) void scan_top(const int* __restrict__ bsum, int* __restrict__ bpre) {
    __shared__ int ps[512];
    int t = threadIdx.x;
    int v = (t < NBLK_SCAN) ? bsum[t] : 0;
    ps[t] = v;
    __syncthreads();
    for (int d = 1; d < 512; d <<= 1) {
        int u = 0;
        if (t >= d) u = ps[t - d];
        __syncthreads();
        ps[t] += u;
        __syncthreads();
    }
    if (t < NBLK_SCAN) bpre[t] = ps[t] - v;   // exclusive
}

__global__ __launch_bounds__(256) void scan_write(const int* __restrict__ cnt, const int* __restrict__ bpre,
                                                  int* __restrict__ offs, int2* __restrict__ rng) {
    __shared__ int ps[256];
    int blk = blockIdx.x, t = threadIdx.x;
    int i0 = blk * SCAN_CHUNK + t * 4;
    int a = 0, b = 0, c = 0, d = 0;
    if (i0 + 3 < TOTC) {
        int4 v = *(const int4*)(cnt + i0);
        a = v.x; b = v.y; c = v.z; d = v.w;
    } else {
        if (i0 + 0 < TOTC) a = cnt[i0 + 0];
        if (i0 + 1 < TOTC) b = cnt[i0 + 1];
        if (i0 + 2 < TOTC) c = cnt[i0 + 2];
        if (i0 + 3 < TOTC) d = cnt[i0 + 3];
    }
    int s = a + b + c + d;
    ps[t] = s;
    __syncthreads();
    for (int dd = 1; dd < 256; dd <<= 1) {
        int u = 0;
        if (t >= dd) u = ps[t - dd];
        __syncthreads();
        ps[t] += u;
        __syncthreads();
    }
    int base = bpre[blk] + ps[t] - s;
    if (i0 + 3 < TOTC) {
        offs[i0 + 0] = base;
        offs[i0 + 1] = base + a;
        offs[i0 + 2] = base + a + b;
        offs[i0 + 3] = base + a + b + c;
        *(int4*)(rng + i0)     = make_int4(base, base + a, base + a, base + a + b);
        *(int4*)(rng + i0 + 2) = make_int4(base + a + b, base + a + b + c,
                                           base + a + b + c, base + s);
    } else {
        if (i0 + 0 < TOTC) { offs[i0 + 0] = base;             rng[i0 + 0] = make_int2(base, base + a); }
        if (i0 + 1 < TOTC) { offs[i0 + 1] = base + a;         rng[i0 + 1] = make_int2(base + a, base + a + b); }
        if (i0 + 2 < TOTC) { offs[i0 + 2] = base + a + b;     rng[i0 + 2] = make_int2(base + a + b, base + a + b + c); }
        if (i0 + 3 < TOTC) { offs[i0 + 3] = base + a + b + c; rng[i0 + 3] = make_int2(base + a + b + c, base + s); }
    }
}

__global__ void scatter_k(const float* __restrict__ xyz, const int* __restrict__ cellid,
                          const int* __restrict__ rank, const int* __restrict__ offs,
                          float4* __restrict__ spos) {
    int t = blockIdx.x * 256 + threadIdx.x;
    if (t >= NTOT) return;
    const float* p = xyz + (size_t)t * 3;
    float x = p[0], y = p[1], z = p[2];
    int pos = offs[cellid[t]] + rank[t];
    spos[pos] = make_float4(x, y, z, __int_as_float(t & (NPTS - 1)));
}

// ---------------- exact KNN: one wave per query ----------------
// R16 = R15 core with ONE change: query<-block mapping is a 14-bit BIT-REVERSAL
// instead of XCD-chunked. Slow queries (escalation / ladder-brute) are CONSECUTIVE
// in sorted cell order; the old mapping put consecutive sorted queries on
// consecutive blocks -> slow clusters serialized on a few CUs of one XCD (the
// drain tail that capped knn at ~114us and read as "low occupancy"). Bit-reversal
// spreads any sorted run uniformly across all CUs. spos (256KB/batch) is
// L2-resident everywhere, so the locality loss is cheap.
__global__ __launch_bounds__(64) void knn_kernel(const float4* __restrict__ spos,
                                                 const int2* __restrict__ rng,
                                                 int* __restrict__ knn,
                                                 float* __restrict__ spatial) {
    __shared__ __align__(16) unsigned long long sel[SEL_CAP];  // 8 KB
    __shared__ __align__(16) unsigned long long sel2[512];     // 4 KB
    int lane = threadIdx.x;
    int bid  = blockIdx.x;
    int s = (int)(__brev((unsigned)bid) >> 18);   // bijective bit-reversal on [0,2^14)
    float4 q = spos[s];
    float qx = q.x, qy = q.y, qz = q.z;
    float qxx = sumsq3(qx, qy, qz);
    int b  = s >> 13;
    int nq = __float_as_int(q.w);
    int cx = min(GD - 1, max(0, (int)floorf((qx - ORGN) * INVH)));
    int cy = min(GD - 1, max(0, (int)floorf((qy - ORGN) * INVH)));
    int cz = min(GD - 1, max(0, (int)floorf((qz - ORGN) * INVH)));
    const int2* rg = rng + b * NCELL;

    float mlx = qx - (ORGN + (float)cx * HCELL);
    float mhx = (ORGN + (float)(cx + 1) * HCELL) - qx;
    float mly = qy - (ORGN + (float)cy * HCELL);
    float mhy = (ORGN + (float)(cy + 1) * HCELL) - qy;
    float mlz = qz - (ORGN + (float)cz * HCELL);
    float mhz = (ORGN + (float)(cz + 1) * HCELL) - qz;
    float margin0 = fminf(fminf(fminf(mlx, mhx), fminf(mly, mhy)), fminf(mlz, mhz));

    int tot = 0, ovf = 0;

    // scan all cells intersecting ball(mfin); append keys < tkfin to sel.
    auto scan_ball = [&](int RB, float mfin, unsigned long long tkfin) {
        if (mfin <= 0.f) return;
        float mfin2 = mfin * mfin;
        int L = 2 * RB + 1, nrows = L * L;
        for (int r0 = 0; r0 < nrows; r0 += 64) {
            int nr = min(64, nrows - r0);
            int rr = r0 + lane;
            int num = 0, start = 0;
            if (rr < nrows) {
                int dzr = rr / L - RB, dyr = rr % L - RB;
                int zc = cz + dzr, yc = cy + dyr;
                if ((unsigned)zc < GD && (unsigned)yc < GD) {
                    float ylo = ORGN + (float)yc * HCELL;
                    float zlo = ORGN + (float)zc * HCELL;
                    float dyl = fmaxf(fmaxf(ylo - qy, qy - (ylo + HCELL)), 0.f);
                    float dzl = fmaxf(fmaxf(zlo - qz, qz - (zlo + HCELL)), 0.f);
                    float rem = mfin2 - dyl * dyl - dzl * dzl;
                    if (rem > -1e-4f) {
                        float xh = sqrtf(fmaxf(rem, 0.f)) + 1e-3f;  // cushion: include boundary cells
                        int xlo = max(0, (int)floorf((qx - xh - ORGN) * INVH));
                        int xhi = min(GD - 1, (int)floorf((qx + xh - ORGN) * INVH));
                        if (xlo <= xhi) {
                            int rowb = (zc * GD + yc) * GD;
                            start = rg[rowb + xlo].x;
                            num   = rg[rowb + xhi].y - start;
                        }
                    }
                }
            }
            int inc = wave_scan_incl(num, lane);
            int ctot = __shfl(inc, 63, 64);
            if (ctot == 0) continue;
            int excl = inc - num;
            // expand candidate index -> slot via 6-step shfl lower_bound, then gather
            auto eg = [&](int base, int& sv, float4& pv, bool& vld) {
                int t = base + lane;
                vld = t < ctot;
                int tc = vld ? t : (ctot - 1);
                int lo = 0, hi = nr - 1;
                #pragma unroll
                for (int st = 0; st < 6; ++st) {
                    int mid = (lo + hi + 1) >> 1;
                    int e = __shfl(excl, mid, 64);
                    bool g = (e <= tc);
                    lo = g ? mid : lo;
                    hi = g ? hi : (mid - 1);
                }
                sv = __shfl(start, lo, 64) + (tc - __shfl(excl, lo, 64));
                pv = spos[sv];
            };
            int s0; float4 p0; bool v0;
            eg(0, s0, p0, v0);
            for (int base = 0; base < ctot; base += 64) {
                int s1 = 0; float4 p1 = p0; bool v1 = false;
                if (base + 64 < ctot) eg(base + 64, s1, p1, v1);   // prefetch next chunk
                float d = pdist4(qx, qy, qz, qxx, p0.x, p0.y, p0.z);
                unsigned long long key = ((unsigned long long)fkey(d) << 27)
                                       | ((unsigned long long)(unsigned)__float_as_int(p0.w) << 14)
                                       | (unsigned)s0;
                bool pass = v0 && (key < tkfin);
                unsigned long long mk = __ballot(pass);
                int cnum = (int)__popcll(mk);
                if (tot + cnum > SEL_CAP) { ovf = 1; return; }
                if (pass) sel[tot + (int)__popcll(mk & ((1ULL << lane) - 1ULL))] = key;
                tot += cnum;
                s0 = s1; p0 = p1; v0 = v1;
            }
        }
    };

    auto count_below = [&](unsigned long long tk) {
        int c = 0;
        for (int t0 = 0; t0 < tot; t0 += 64) {
            int tt = t0 + lane;
            if (tt < tot) c += (sel[tt] < tk) ? 1 : 0;
        }
        for (int o = 32; o > 0; o >>= 1) c += __shfl_xor(c, o, 64);
        return c;
    };

    // ---- phase 1: ball(margin(RSTART)) ----
    float mfin1 = margin0 + (float)RSTART * HCELL;
    unsigned long long tkf1 = (mfin1 > 0.f) ? tkmake(mfin1) : 0ULL;
    if (tkf1) scan_ball(RSTART, mfin1, tkf1);

    unsigned long long tkey_sel = ~0ULL;
    int csel = 0;
    bool have = false;
    if (!ovf && tot >= 16) {
        float mA = margin0 + 1.0f * HCELL;
        if (mA > 0.f) {
            unsigned long long tkA = tkmake(mA);
            int cA = count_below(tkA);
            if (cA >= 16) { tkey_sel = tkA; csel = cA; have = true; }
        }
        if (!have) { tkey_sel = ~0ULL; csel = tot; have = true; }   // all of sel (< margin(RSTART))
    }
    if (!have && !ovf) {
        // ---- escalation: reset + rescan ball(margin(RESC)) ----
        tot = 0;
        float mfin4 = margin0 + (float)RESC * HCELL;
        unsigned long long tkf4 = (mfin4 > 0.f) ? tkmake(mfin4) : 0ULL;
        if (tkf4) scan_ball(RESC, mfin4, tkf4);
        if (!ovf && tot >= 16) {
            float mB = margin0 + (float)(RESC - 1) * HCELL;
            if (mB > 0.f) {
                unsigned long long tkB = tkmake(mB);
                int cB = count_below(tkB);
                if (cB >= 16) { tkey_sel = tkB; csel = cB; have = true; }
            }
            if (!have) { tkey_sel = ~0ULL; csel = tot; have = true; }
        }
    }

    if (!have) {
        // ---- two-pass ladder brute over all NPTS of this batch (R10-proven) ----
        const float LADR[16] = {0.35f, 0.4725f, 0.637875f, 0.86113125f,
                                1.1625272f, 1.5694117f, 2.1187058f, 2.8602529f,
                                3.8613414f, 5.2128109f, 7.0372947f, 9.5003478f,
                                12.825470f, 17.314384f, 23.374418f, 31.555464f};
        int sbase = b << 13;
        int cc[16];
        #pragma unroll
        for (int k = 0; k < 16; ++k) cc[k] = 0;
        for (int i0 = 0; i0 < NPTS; i0 += 64) {
            float4 p = spos[sbase + i0 + lane];
            float d = pdist4(qx, qy, qz, qxx, p.x, p.y, p.z);
            #pragma unroll
            for (int k = 0; k < 16; ++k) cc[k] += (d < LADR[k] * LADR[k]) ? 1 : 0;
        }
        #pragma unroll
        for (int k = 0; k < 16; ++k)
            for (int o = 32; o > 0; o >>= 1) cc[k] += __shfl_xor(cc[k], o, 64);
        float Tq = LADR[15] * LADR[15]; int cL = cc[15];
        #pragma unroll
        for (int k = 14; k >= 0; --k) if (cc[k] >= 16) { Tq = LADR[k] * LADR[k]; cL = cc[k]; }
        if (cL <= SEL_CAP) {
            tot = 0;
            for (int i0 = 0; i0 < NPTS; i0 += 64) {
                int idx = sbase + i0 + lane;
                float4 p = spos[idx];
                float d = pdist4(qx, qy, qz, qxx, p.x, p.y, p.z);
                bool pass = (d < Tq);
                unsigned long long key = ((unsigned long long)fkey(d) << 27)
                                       | ((unsigned long long)(unsigned)__float_as_int(p.w) << 14)
                                       | (unsigned)idx;
                unsigned long long mk = __ballot(pass);
                if (pass) sel[tot + (int)__popcll(mk & ((1ULL << lane) - 1ULL))] = key;
                tot += (int)__popcll(mk);
            }
            tkey_sel = ~0ULL;
            csel = tot;
        } else {
            // ultra-rare capacity fallback: per-lane top16 in sel region + 16-round extract
            unsigned long long* mybuf = sel + lane;   // element j at [j*64]
            unsigned long long minkey = ~0ULL, maxkey = 0;
            int nbuf = 0;
            for (int i = lane; i < NPTS; i += 64) {
                float4 p = spos[sbase + i];
                float d = pdist4(qx, qy, qz, qxx, p.x, p.y, p.z);
                unsigned long long key = ((unsigned long long)fkey(d) << 27)
                                       | ((unsigned long long)(unsigned)__float_as_int(p.w) << 14)
                                       | (unsigned)(sbase + i);
                if (nbuf < 16) {
                    mybuf[(size_t)nbuf * 64] = key;
                    ++nbuf;
                    minkey = (key < minkey) ? key : minkey;
                    maxkey = (key > maxkey) ? key : maxkey;
                } else if (key < maxkey) {
                    unsigned long long vmax = 0, v2 = 0;
                    int pmax = 0;
                    #pragma unroll
                    for (int j = 0; j < 16; ++j) {
                        unsigned long long v = mybuf[(size_t)j * 64];
                        if (v > vmax) { v2 = vmax; vmax = v; pmax = j; }
                        else if (v > v2) { v2 = v; }
                    }
                    mybuf[(size_t)pmax * 64] = key;
                    maxkey = (key > v2) ? key : v2;
                    minkey = (key < minkey) ? key : minkey;
                }
            }
            unsigned long long keep = ~0ULL;
            for (int k = 0; k < 16; ++k) {
                unsigned long long m = minkey;
                for (int o = 32; o > 0; o >>= 1) {
                    unsigned long long pv = shflx64(m, o);
                    m = (pv < m) ? pv : m;
                }
                unsigned long long bal = __ballot(minkey == m);
                int wl = __ffsll((long long)bal) - 1;
                if (lane == wl) {
                    int pos = 0;
                    for (int j = 0; j < nbuf; ++j) if (mybuf[(size_t)j * 64] == m) pos = j;
                    --nbuf;
                    mybuf[(size_t)pos * 64] = mybuf[(size_t)nbuf * 64];
                    unsigned long long nm = ~0ULL;
                    for (int j = 0; j < nbuf; ++j) {
                        unsigned long long v = mybuf[(size_t)j * 64];
                        nm = (v < nm) ? v : nm;
                    }
                    minkey = nm;
                }
                if (lane == k) keep = m;
            }
            float rx = 0.f, ry = 0.f, rz = 0.f, rd = 0.f;
            if (lane < 16) {
                int sp = (int)(keep & 0x3FFFu);
                int oi = (int)((keep >> 14) & 0x1FFFu);
                float4 p = spos[sp];
                rx = p.x - qx; ry = p.y - qy; rz = p.z - qz;
                rd = sqrtf(__fadd_rn(__fadd_rn(__fmul_rn(rx, rx), __fmul_rn(ry, ry)), __fmul_rn(rz, rz)));
                knn[(((size_t)b << 13) + nq) * 16 + lane] = oi;
            }
            for (int o = 8; o > 0; o >>= 1) {
                rx += __shfl_xor(rx, o, 64);
                ry += __shfl_xor(ry, o, 64);
                rz += __shfl_xor(rz, o, 64);
                rd += __shfl_xor(rd, o, 64);
            }
            if (lane == 0) {
                const float inv16 = 0.0625f;
                spatial[((size_t)b * 4 + 0) * NPTS + nq] = rx * inv16;
                spatial[((size_t)b * 4 + 1) * NPTS + nq] = ry * inv16;
                spatial[((size_t)b * 4 + 2) * NPTS + nq] = rz * inv16;
                spatial[((size_t)b * 4 + 3) * NPTS + nq] = rd * inv16;
            }
            return;
        }
    }

    // -------- shared selection: compact keys < tkey_sel, then rank-count --------
    const unsigned long long* src = sel;
    int m = tot;
    if (tkey_sel != ~0ULL && csel <= 512) {
        int w = 0;
        for (int t0 = 0; t0 < tot; t0 += 64) {
            int tt = t0 + lane;
            unsigned long long v = (tt < tot) ? sel[tt] : ~0ULL;
            bool pass = (tt < tot) && (v < tkey_sel);
            unsigned long long mk = __ballot(pass);
            if (pass) sel2[w + (int)__popcll(mk & ((1ULL << lane) - 1ULL))] = v;
            w += (int)__popcll(mk);
        }
        asm volatile("s_waitcnt lgkmcnt(0)" ::: "memory");
        __builtin_amdgcn_sched_barrier(0);
        src = sel2; m = w;
        tkey_sel = ~0ULL;   // compacted list is fully qualified
    }
    float rxs = 0.f, rys = 0.f, rzs = 0.f, rds = 0.f;
    for (int t0 = 0; t0 < m; t0 += 64) {
        int tt = t0 + lane;
        if (tt < m) {
            unsigned long long kt = src[tt];
            if (kt < tkey_sel) {
                int rr = 0;
                for (int j = 0; j < m; ++j) rr += (src[j] < kt) ? 1 : 0;   // broadcast reads
                if (rr < 16) {
                    int sp = (int)(kt & 0x3FFFu);
                    int oi = (int)((kt >> 14) & 0x1FFFu);
                    float4 p = spos[sp];
                    float dx = p.x - qx, dy = p.y - qy, dz = p.z - qz;
                    float dl = sqrtf(__fadd_rn(__fadd_rn(__fmul_rn(dx, dx), __fmul_rn(dy, dy)), __fmul_rn(dz, dz)));
                    knn[(((size_t)b << 13) + nq) * 16 + rr] = oi;
                    rxs += dx; rys += dy; rzs += dz; rds += dl;
                }
            }
        }
    }
    for (int o = 32; o > 0; o >>= 1) {
        rxs += __shfl_xor(rxs, o, 64);
        rys += __shfl_xor(rys, o, 64);
        rzs += __shfl_xor(rzs, o, 64);
        rds += __shfl_xor(rds, o, 64);
    }
    if (lane == 0) {
        const float inv16 = 0.0625f;
        spatial[((size_t)b * 4 + 0) * NPTS + nq] = rxs * inv16;
        spatial[((size_t)b * 4 + 1) * NPTS + nq] = rys * inv16;
        spatial[((size_t)b * 4 + 2) * NPTS + nq] = rzs * inv16;
        spatial[((size_t)b * 4 + 3) * NPTS + nq] = rds * inv16;
    }
}

// ---------------- x[B,C,N] -> xT[B,N,C] ----------------
__global__ void transpose_k(const float* __restrict__ x, float* __restrict__ xT) {
    __shared__ float tl[32][33];
    int b = blockIdx.z;
    int n0 = blockIdx.x * 32, c0 = blockIdx.y * 32;
    int tx = threadIdx.x, ty = threadIdx.y;
    const float* xb = x + (size_t)b * 128 * NN;
    float* xtb = xT + (size_t)b * NN * 128;
    for (int i = 0; i < 32; i += 8) tl[ty + i][tx] = xb[(size_t)(c0 + ty + i) * NN + n0 + tx];
    __syncthreads();
    for (int i = 0; i < 32; i += 8) xtb[(size_t)(n0 + ty + i) * 128 + c0 + tx] = tl[tx][ty + i];
}

// ---------------- max_k(x[:,idx_k]) - x  -> md[B,128,N] ----------------
__global__ __launch_bounds__(256) void md_k(const float* __restrict__ xT,
                                            const int* __restrict__ knn,
                                            float* __restrict__ md) {
    __shared__ int ki[8][16];
    __shared__ float smd[8][132];
    int b = blockIdx.y;
    int n0 = blockIdx.x * 8;
    int tid = threadIdx.x;
    if (tid < 128) ki[tid >> 4][tid & 15] = knn[(((size_t)b << 13) + n0 + (tid >> 4)) * 16 + (tid & 15)];
    __syncthreads();
    int nl = tid >> 5;
    int c4 = (tid & 31) * 4;
    const float* xb = xT + (size_t)b * NPTS * 128;
    float4 m = make_float4(-3.0e38f, -3.0e38f, -3.0e38f, -3.0e38f);
    #pragma unroll
    for (int k = 0; k < 16; ++k) {
        const float4 g = *(const float4*)(xb + (size_t)ki[nl][k] * 128 + c4);
        m.x = fmaxf(m.x, g.x); m.y = fmaxf(m.y, g.y); m.z = fmaxf(m.z, g.z); m.w = fmaxf(m.w, g.w);
    }
    const float4 own = *(const float4*)(xb + (size_t)(n0 + nl) * 128 + c4);
    m.x -= own.x; m.y -= own.y; m.z -= own.z; m.w -= own.w;
    *(float4*)(&smd[nl][c4]) = m;
    __syncthreads();
    for (int r = 0; r < 4; ++r) {
        int c = (tid >> 3) + 32 * r;
        int n2 = tid & 7;
        md[((size_t)b * 128 + c) * NN + n0 + n2] = smd[n2][c];
    }
}

// ---------------- fold conv-bias + BN into per-channel scale/shift ----------------
__global__ void prep_k(const float* bb1, const float* g1, const float* be1, const float* m1, const float* v1,
                       const float* bb2, const float* g2, const float* be2, const float* m2, const float* v2,
                       const float* sb1, const float* gs,  const float* bes, const float* ms, const float* vs,
                       const float* sb2,
                       const float* ab1, const float* ga,  const float* bea, const float* ma, const float* va,
                       const float* ab2, float* sc) {
    int t = threadIdx.x;
    if (t < 128) {
        float i1 = g1[t] / sqrtf(v1[t] + 1e-5f);
        sc[t] = i1;        sc[128 + t] = bb1[t] * i1 + be1[t] - m1[t] * i1;
        float i2 = g2[t] / sqrtf(v2[t] + 1e-5f);
        sc[256 + t] = i2;  sc[384 + t] = bb2[t] * i2 + be2[t] - m2[t] * i2;
        sc[832 + t] = 1.0f; sc[960 + t] = ab2[t];
    }
    if (t < 32) {
        float is = gs[t] / sqrtf(vs[t] + 1e-5f);
        sc[512 + t] = is;  sc[544 + t] = sb1[t] * is + bes[t] - ms[t] * is;
    }
    if (t < 64) {
        sc[576 + t] = 1.0f; sc[640 + t] = sb2[t];
        float ia = ga[t] / sqrtf(va[t] + 1e-5f);
        sc[704 + t] = ia;  sc[768 + t] = ab1[t] * ia + bea[t] - ma[t] * ia;
    }
}

// ---------------- generic 1x1-conv (+folded BN, activation) — spatial MLP only ----------------
template <int O, int K, int TILE_N, int SPLIT, int ACT>
__global__ __launch_bounds__(256) void conv_bn(const float* __restrict__ srcA,
                                               const float* __restrict__ srcB,
                                               const float* __restrict__ W,
                                               const float* __restrict__ scale,
                                               const float* __restrict__ shift,
                                               float* __restrict__ out) {
    constexpr int KC  = (K < 64) ? K : 64;
    constexpr int NT4 = TILE_N / 4;
    constexpr int O4  = O / 4;
    static_assert(NT4 * O4 == 256, "thread mapping");
    __shared__ float wT[KC][O + 4];
    __shared__ float inT[KC][TILE_N];
    int tid = threadIdx.x;
    int b = blockIdx.z;
    int n0 = blockIdx.x * TILE_N;
    int n_thr = tid % NT4;
    int o_thr = tid / NT4;
    float acc[4][4] = {{0.f, 0.f, 0.f, 0.f}, {0.f, 0.f, 0.f, 0.f}, {0.f, 0.f, 0.f, 0.f}, {0.f, 0.f, 0.f, 0.f}};

    for (int k0 = 0; k0 < K; k0 += KC) {
        for (int idx = tid; idx < KC * O; idx += 256) {
            int cc = idx % KC;
            int o  = idx / KC;
            wT[cc][o] = W[(size_t)o * K + k0 + cc];
        }
        for (int idx = tid; idx < KC * NT4; idx += 256) {
            int cc = idx / NT4;
            int nf = idx % NT4;
            int cg = k0 + cc;
            const float* src = (cg < SPLIT)
                ? (srcA + ((size_t)b * SPLIT + cg) * NN)
                : (srcB + ((size_t)b * (K - SPLIT) + (cg - SPLIT)) * NN);
            *(float4*)(&inT[cc][nf * 4]) = *(const float4*)(src + n0 + nf * 4);
        }
        __syncthreads();
        #pragma unroll 8
        for (int c = 0; c < KC; ++c) {
            float4 wv = *(const float4*)(&wT[c][o_thr * 4]);
            float4 iv = *(const float4*)(&inT[c][n_thr * 4]);
            acc[0][0] = fmaf(wv.x, iv.x, acc[0][0]); acc[0][1] = fmaf(wv.x, iv.y, acc[0][1]);
            acc[0][2] = fmaf(wv.x, iv.z, acc[0][2]); acc[0][3] = fmaf(wv.x, iv.w, acc[0][3]);
            acc[1][0] = fmaf(wv.y, iv.x, acc[1][0]); acc[1][1] = fmaf(wv.y, iv.y, acc[1][1]);
            acc[1][2] = fmaf(wv.y, iv.z, acc[1][2]); acc[1][3] = fmaf(wv.y, iv.w, acc[1][3]);
            acc[2][0] = fmaf(wv.z, iv.x, acc[2][0]); acc[2][1] = fmaf(wv.z, iv.y, acc[2][1]);
            acc[2][2] = fmaf(wv.z, iv.z, acc[2][2]); acc[2][3] = fmaf(wv.z, iv.w, acc[2][3]);
            acc[3][0] = fmaf(wv.w, iv.x, acc[3][0]); acc[3][1] = fmaf(wv.w, iv.y, acc[3][1]);
            acc[3][2] = fmaf(wv.w, iv.z, acc[3][2]); acc[3][3] = fmaf(wv.w, iv.w, acc[3][3]);
        }
        __syncthreads();
    }
    #pragma unroll
    for (int j = 0; j < 4; ++j) {
        int o = o_thr * 4 + j;
        float scv = scale[o], shv = shift[o];
        float4 v;
        v.x = fmaf(acc[j][0], scv, shv);
        v.y = fmaf(acc[j][1], scv, shv);
        v.z = fmaf(acc[j][2], scv, shv);
        v.w = fmaf(acc[j][3], scv, shv);
        size_t obase = ((size_t)b * O + o) * NN + n0 + n_thr * 4;
        if (ACT == 1) {
            v.x = fmaxf(v.x, 0.f); v.y = fmaxf(v.y, 0.f); v.z = fmaxf(v.z, 0.f); v.w = fmaxf(v.w, 0.f);
        }
        *(float4*)(out + obase) = v;
    }
}

#define FMA16(ACCV, WV, IV) \
    ACCV[0][0] = fmaf(WV.x, IV.x, ACCV[0][0]); ACCV[0][1] = fmaf(WV.x, IV.y, ACCV[0][1]); \
    ACCV[0][2] = fmaf(WV.x, IV.z, ACCV[0][2]); ACCV[0][3] = fmaf(WV.x, IV.w, ACCV[0][3]); \
    ACCV[1][0] = fmaf(WV.y, IV.x, ACCV[1][0]); ACCV[1][1] = fmaf(WV.y, IV.y, ACCV[1][1]); \
    ACCV[1][2] = fmaf(WV.y, IV.z, ACCV[1][2]); ACCV[1][3] = fmaf(WV.y, IV.w, ACCV[1][3]); \
    ACCV[2][0] = fmaf(WV.z, IV.x, ACCV[2][0]); ACCV[2][1] = fmaf(WV.z, IV.y, ACCV[2][1]); \
    ACCV[2][2] = fmaf(WV.z, IV.z, ACCV[2][2]); ACCV[2][3] = fmaf(WV.z, IV.w, ACCV[2][3]); \
    ACCV[3][0] = fmaf(WV.w, IV.x, ACCV[3][0]); ACCV[3][1] = fmaf(WV.w, IV.y, ACCV[3][1]); \
    ACCV[3][2] = fmaf(WV.w, IV.z, ACCV[3][2]); ACCV[3][3] = fmaf(WV.w, IV.w, ACCV[3][3])

// ---------------- fused boundary net: [x;md] 256->128 (bn,relu) -> 128->128 (bn,relu) ----------------
__global__ __launch_bounds__(256) void fused_boundary(const float* __restrict__ x,
                                                      const float* __restrict__ md,
                                                      const float* __restrict__ W1,
                                                      const float* __restrict__ W2,
                                                      const float* __restrict__ sc,
                                                      float* __restrict__ y2b) {
    __shared__ float wT[64][132];    // 33.8 KB
    __shared__ float inT[64][32];    // 8 KB
    __shared__ float y1t[128][32];   // 16 KB
    int tid = threadIdx.x;
    int b = blockIdx.z;
    int n0 = blockIdx.x * 32;
    int n_thr = tid % 8;
    int o_thr = tid / 8;             // 0..31
    float acc[4][4] = {{0.f,0.f,0.f,0.f},{0.f,0.f,0.f,0.f},{0.f,0.f,0.f,0.f},{0.f,0.f,0.f,0.f}};

    // stage 1: [x;md] 256 -> 128, bn+relu -> y1t
    for (int k0 = 0; k0 < 256; k0 += 64) {
        for (int idx = tid; idx < 64 * 128; idx += 256) {
            int cc = idx % 64;
            int o  = idx / 64;
            wT[cc][o] = W1[(size_t)o * 256 + k0 + cc];
        }
        for (int idx = tid; idx < 64 * 8; idx += 256) {
            int cc = idx / 8;
            int nf = idx % 8;
            int cg = k0 + cc;
            const float* src = (cg < 128)
                ? (x  + ((size_t)b * 128 + cg) * NN)
                : (md + ((size_t)b * 128 + (cg - 128)) * NN);
            *(float4*)(&inT[cc][nf * 4]) = *(const float4*)(src + n0 + nf * 4);
        }
        __syncthreads();
        #pragma unroll 8
        for (int c = 0; c < 64; ++c) {
            float4 wv = *(const float4*)(&wT[c][o_thr * 4]);
            float4 iv = *(const float4*)(&inT[c][n_thr * 4]);
            FMA16(acc, wv, iv);
        }
        __syncthreads();
    }
    #pragma unroll
    for (int j = 0; j < 4; ++j) {
        int o = o_thr * 4 + j;
        float scv = sc[o], shv = sc[128 + o];
        float4 v;
        v.x = fmaxf(fmaf(acc[j][0], scv, shv), 0.f);
        v.y = fmaxf(fmaf(acc[j][1], scv, shv), 0.f);
        v.z = fmaxf(fmaf(acc[j][2], scv, shv), 0.f);
        v.w = fmaxf(fmaf(acc[j][3], scv, shv), 0.f);
        *(float4*)(&y1t[o][n_thr * 4]) = v;
    }
    __syncthreads();

    // stage 2: 128 -> 128, bn+relu -> y2b (reads y1t from LDS)
    float a2[4][4] = {{0.f,0.f,0.f,0.f},{0.f,0.f,0.f,0.f},{0.f,0.f,0.f,0.f},{0.f,0.f,0.f,0.f}};
    for (int k0 = 0; k0 < 128; k0 += 64) {
        for (int idx = tid; idx < 64 * 128; idx += 256) {
            int cc = idx % 64;
            int o  = idx / 64;
            wT[cc][o] = W2[(size_t)o * 128 + k0 + cc];
        }
        __syncthreads();
        #pragma unroll 8
        for (int c = 0; c < 64; ++c) {
            float4 wv = *(const float4*)(&wT[c][o_thr * 4]);
            float4 iv = *(const float4*)(&y1t[k0 + c][n_thr * 4]);
            FMA16(a2, wv, iv);
        }
        __syncthreads();
    }
    #pragma unroll
    for (int j = 0; j < 4; ++j) {
        int o = o_thr * 4 + j;
        float scv = sc[256 + o], shv = sc[384 + o];
        float4 v;
        v.x = fmaxf(fmaf(a2[j][0], scv, shv), 0.f);
        v.y = fmaxf(fmaf(a2[j][1], scv, shv), 0.f);
        v.z = fmaxf(fmaf(a2[j][2], scv, shv), 0.f);
        v.w = fmaxf(fmaf(a2[j][3], scv, shv), 0.f);
        *(float4*)(y2b + ((size_t)b * 128 + o) * NN + n0 + n_thr * 4) = v;
    }
}

// ---------------- fused attention: [x;sfeat] 192->64 (bn,relu) -> 64->128 sigmoid + final fuse ----------------
__global__ __launch_bounds__(256) void fused_attn(const float* __restrict__ x,
                                                  const float* __restrict__ sfb,
                                                  const float* __restrict__ W1,
                                                  const float* __restrict__ W2,
                                                  const float* __restrict__ sc,
                                                  const float* __restrict__ y2b,
                                                  float* __restrict__ dout) {
    __shared__ float wT[64][68];     // 17.4 KB
    __shared__ float inT[64][64];    // 16 KB
    __shared__ float a1t[64][64];    // 16 KB
    int tid = threadIdx.x;
    int b = blockIdx.z;
    int n0 = blockIdx.x * 64;
    int n_thr = tid % 16;
    int o_thr = tid / 16;            // 0..15
    float acc[4][4] = {{0.f,0.f,0.f,0.f},{0.f,0.f,0.f,0.f},{0.f,0.f,0.f,0.f},{0.f,0.f,0.f,0.f}};

    // stage 1: [x;sfb] 192 -> 64, bn+relu -> a1t
    for (int k0 = 0; k0 < 192; k0 += 64) {
        for (int idx = tid; idx < 64 * 64; idx += 256) {
            int cc = idx % 64;
            int o  = idx / 64;
            wT[cc][o] = W1[(size_t)o * 192 + k0 + cc];
        }
        for (int idx = tid; idx < 64 * 16; idx += 256) {
            int cc = idx / 16;
            int nf = idx % 16;
            int cg = k0 + cc;
            const float* src = (cg < 128)
                ? (x   + ((size_t)b * 128 + cg) * NN)
                : (sfb + ((size_t)b * 64 + (cg - 128)) * NN);
            *(float4*)(&inT[cc][nf * 4]) = *(const float4*)(src + n0 + nf * 4);
        }
        __syncthreads();
        #pragma unroll 8
        for (int c = 0; c < 64; ++c) {
            float4 wv = *(const float4*)(&wT[c][o_thr * 4]);
            float4 iv = *(const float4*)(&inT[c][n_thr * 4]);
            FMA16(acc, wv, iv);
        }
        __syncthreads();
    }
    #pragma unroll
    for (int j = 0; j < 4; ++j) {
        int o = o_thr * 4 + j;
        float scv = sc[704 + o], shv = sc[768 + o];
        float4 v;
        v.x = fmaxf(fmaf(acc[j][0], scv, shv), 0.f);
        v.y = fmaxf(fmaf(acc[j][1], scv, shv), 0.f);
        v.z = fmaxf(fmaf(acc[j][2], scv, shv), 0.f);
        v.w = fmaxf(fmaf(acc[j][3], scv, shv), 0.f);
        *(float4*)(&a1t[o][n_thr * 4]) = v;
    }
    __syncthreads();

    // stage 2: 64 -> 128 in two o-halves; sigmoid + dout = x + y2*attn
    for (int oh = 0; oh < 128; oh += 64) {
        for (int idx = tid; idx < 64 * 64; idx += 256) {
            int cc = idx % 64;
            int o  = idx / 64;
            wT[cc][o] = W2[(size_t)(oh + o) * 64 + cc];
        }
        __syncthreads();
        float a2[4][4] = {{0.f,0.f,0.f,0.f},{0.f,0.f,0.f,0.f},{0.f,0.f,0.f,0.f},{0.f,0.f,0.f,0.f}};
        #pragma unroll 8
        for (int c = 0; c < 64; ++c) {
            float4 wv = *(const float4*)(&wT[c][o_thr * 4]);
            float4 iv = *(const float4*)(&a1t[c][n_thr * 4]);
            FMA16(a2, wv, iv);
        }
        #pragma unroll
        for (int j = 0; j < 4; ++j) {
            int o = oh + o_thr * 4 + j;
            float scv = sc[832 + o], shv = sc[960 + o];
            float4 v;
            v.x = fmaf(a2[j][0], scv, shv);
            v.y = fmaf(a2[j][1], scv, shv);
            v.z = fmaf(a2[j][2], scv, shv);
            v.w = fmaf(a2[j][3], scv, shv);
            size_t obase = ((size_t)b * 128 + o) * NN + n0 + n_thr * 4;
            float4 xr = *(const float4*)(x + obase);
            float4 yr = *(const float4*)(y2b + obase);
            v.x = xr.x + yr.x / (1.f + __expf(-v.x));
            v.y = xr.y + yr.y / (1.f + __expf(-v.y));
            v.z = xr.z + yr.z / (1.f + __expf(-v.z));
            v.w = xr.w + yr.w / (1.f + __expf(-v.w));
            *(float4*)(dout + obase) = v;
        }
        __syncthreads();   // wT reads done before next half reloads
    }
}

extern "C" void kernel_launch(void* const* d_in, const int* in_sizes, int n_in,
                              void* d_out, int out_size, void* d_ws, size_t ws_size,
                              hipStream_t stream) {
    (void)in_sizes; (void)n_in; (void)out_size; (void)ws_size;
    const float* x    = (const float*)d_in[0];
    const float* xyz  = (const float*)d_in[1];
    const float* bw1  = (const float*)d_in[2];
    const float* bb1  = (const float*)d_in[3];
    const float* bn1g = (const float*)d_in[4];
    const float* bn1b = (const float*)d_in[5];
    const float* bn1m = (const float*)d_in[6];
    const float* bn1v = (const float*)d_in[7];
    const float* bw2  = (const float*)d_in[8];
    const float* bb2  = (const float*)d_in[9];
    const float* bn2g = (const float*)d_in[10];
    const float* bn2b = (const float*)d_in[11];
    const float* bn2m = (const float*)d_in[12];
    const float* bn2v = (const float*)d_in[13];
    const float* sw1  = (const float*)d_in[14];
    const float* sb1  = (const float*)d_in[15];
    const float* sbng = (const float*)d_in[16];
    const float* sbnb = (const float*)d_in[17];
    const float* sbnm = (const float*)d_in[18];
    const float* sbnv = (const float*)d_in[19];
    const float* sw2  = (const float*)d_in[20];
    const float* sb2  = (const float*)d_in[21];
    const float* aw1  = (const float*)d_in[22];
    const float* ab1  = (const float*)d_in[23];
    const float* abng = (const float*)d_in[24];
    const float* abnb = (const float*)d_in[25];
    const float* abnm = (const float*)d_in[26];
    const float* abnv = (const float*)d_in[27];
    const float* aw2  = (const float*)d_in[28];
    const float* ab2  = (const float*)d_in[29];

    char* ws = (char*)d_ws;
    int*    cnt    = (int*)(ws + OFF_CNT);
    int*    offs   = (int*)(ws + OFF_OFFS);
    int*    cellid = (int*)(ws + OFF_CELLID);
    int*    rank   = (int*)(ws + OFF_RANK);
    float4* spos   = (float4*)(ws + OFF_SPOS);
    int*    knn    = (int*)(ws + OFF_KNN);
    float*  spat   = (float*)(ws + OFF_SPATIAL);
    float*  xT     = (float*)(ws + OFF_XT);
    float*  md     = (float*)(ws + OFF_MD);
    float*  s1b    = (float*)(ws + OFF_S1);
    float*  sfb    = (float*)(ws + OFF_SF);
    float*  y2b    = (float*)(ws + OFF_Y2);
    float*  sc     = (float*)(ws + OFF_SC);
    int*    bsum   = (int*)(ws + OFF_BSUM);
    int*    bpre   = (int*)(ws + OFF_BPRE);
    int2*   rng    = (int2*)(ws + OFF_RNG);
    float*  dout   = (float*)d_out;

    hipMemsetAsync(cnt, 0, (size_t)TOTC * 4, stream);
    cell_build<<<dim3((NTOT + 255) / 256), 256, 0, stream>>>(xyz, cnt, cellid, rank);
    scan_sums<<<dim3(NBLK_SCAN), 256, 0, stream>>>(cnt, bsum);
    scan_top<<<dim3(1), 512, 0, stream>>>(bsum, bpre);
    scan_write<<<dim3(NBLK_SCAN), 256, 0, stream>>>(cnt, bpre, offs, rng);
    scatter_k<<<dim3((NTOT + 255) / 256), 256, 0, stream>>>(xyz, cellid, rank, offs, spos);
    knn_kernel<<<dim3(NTOT), 64, 0, stream>>>(spos, rng, knn, spat);
    transpose_k<<<dim3(NPTS / 32, 128 / 32, NB), dim3(32, 8), 0, stream>>>(x, xT);
    md_k<<<dim3(NPTS / 8, NB), 256, 0, stream>>>(xT, knn, md);
    prep_k<<<1, 128, 0, stream>>>(bb1, bn1g, bn1b, bn1m, bn1v,
                                  bb2, bn2g, bn2b, bn2m, bn2v,
                                  sb1, sbng, sbnb, sbnm, sbnv,
                                  sb2,
                                  ab1, abng, abnb, abnm, abnv,
                                  ab2, sc);
    // spatial MLP: 4->32 (bn,relu), 32->64
    conv_bn<32, 4, 128, 4, 1><<<dim3(NPTS / 128, 1, NB), 256, 0, stream>>>(
        spat, spat, sw1, sc + 512, sc + 544, s1b);
    conv_bn<64, 32, 64, 32, 0><<<dim3(NPTS / 64, 1, NB), 256, 0, stream>>>(
        s1b, s1b, sw2, sc + 576, sc + 640, sfb);
    // fused boundary net: [x;md] 256->128 (bn,relu) -> 128->128 (bn,relu)
    fused_boundary<<<dim3(NPTS / 32, 1, NB), 256, 0, stream>>>(x, md, bw1, bw2, sc, y2b);
    // fused attention: [x;sfeat] 192->64 (bn,relu) -> 64->128 sigmoid + final fuse
    fused_attn<<<dim3(NPTS / 64, 1, NB), 256, 0, stream>>>(x, sfb, aw1, aw2, sc, y2b, dout);
}